// Round 4
// baseline (498.463 us; speedup 1.0000x reference)
//
#include <hip/hip_runtime.h>
#include <hip/hip_bf16.h>
#include <math.h>

// Shapes: B=1, N=64, L=256, nf=64, npj=32, nfo=128
// All GEMM-shaped work on bf16 MFMA (16x16x32). All intermediate activations bf16.
// Fragment conventions (validated rounds 1-3):
//   A-frag: row = lane&15, k = (lane>>4)*8 + j
//   B-frag: col = lane&15, k = (lane>>4)*8 + j
//   C-frag: col = lane&15, row = (lane>>4)*4 + r

typedef __attribute__((ext_vector_type(8))) short bf16x8;
typedef __attribute__((ext_vector_type(4))) float f32x4;

__device__ __forceinline__ float eluf(float x) { return x > 0.f ? x : expm1f(x); }
__device__ __forceinline__ ushort f2b(float f) {
    unsigned u = __float_as_uint(f);
    return (ushort)((u + 0x7fff + ((u >> 16) & 1)) >> 16);
}
__device__ __forceinline__ float b2f(ushort u) {
    return __uint_as_float(((unsigned)u) << 16);
}

// ---------------------------------------------------------------- x_down -> xdT bf16
__global__ __launch_bounds__(256) void k_xdown(
    const float* __restrict__ msa, const float* __restrict__ W1,
    const float* __restrict__ b1, ushort* __restrict__ xdT)
{
    __shared__ float w1s[32 * 65];
    const int tid = threadIdx.x;
    for (int t = tid; t < 2048; t += 256) w1s[(t >> 6) * 65 + (t & 63)] = W1[t];
    __syncthreads();
    const int id = blockIdx.x * 256 + tid;
    const int p = id & 31, l = (id >> 5) & 255, n = id >> 13;
    const float* mrow = msa + (((n << 8) + l) << 6);
    const float* wrow = w1s + p * 65;
    float s = 0.f;
#pragma unroll 8
    for (int f = 0; f < 64; ++f) s += mrow[f] * wrow[f];
    xdT[(((l << 5) + p) << 6) + n] = f2b(s + b1[p]);
}

// ---------------------------------------------------------------- feat_1d
__global__ __launch_bounds__(256) void k_feat(
    const float* __restrict__ msa, float* __restrict__ feat)
{
    const int id = blockIdx.x * 256 + threadIdx.x;   // 32768
    const int c = id & 127, l = id >> 7;
    float v;
    if (c < 64) {
        float s = 0.f;
        for (int n = 0; n < 64; ++n) s += msa[(((n << 8) + l) << 6) + c];
        v = s * (1.f / 64.f);
    } else {
        v = msa[(l << 6) + (c - 64)];
    }
    feat[id] = v;
}

// ------------------------------------------- S1[o]=sum_c g*W2, S2[o]=sum_c be*W2 + b2
__global__ __launch_bounds__(256) void k_g2(
    const float* __restrict__ W2, const float* __restrict__ g_ln,
    const float* __restrict__ be_ln, const float* __restrict__ b2,
    float* __restrict__ S1, float* __restrict__ S2)
{
    const int o = blockIdx.x, tid = threadIdx.x;
    float s1 = 0.f, s2 = 0.f;
    for (int c = tid; c < 1024; c += 256) {
        float w = W2[o * 1024 + c];
        s1 += g_ln[c] * w;
        s2 += be_ln[c] * w;
    }
#pragma unroll
    for (int off = 32; off; off >>= 1) { s1 += __shfl_down(s1, off); s2 += __shfl_down(s2, off); }
    __shared__ float r1[4], r2[4];
    if ((tid & 63) == 0) { r1[tid >> 6] = s1; r2[tid >> 6] = s2; }
    __syncthreads();
    if (tid == 0) {
        S1[o] = r1[0] + r1[1] + r1[2] + r1[3];
        S2[o] = r2[0] + r2[1] + r2[2] + r2[3] + b2[o];
    }
}

// ------------------------------------------- G2 in B-fragment bf16 layout
__global__ __launch_bounds__(256) void k_g2swz(
    const float* __restrict__ W2, const float* __restrict__ g_ln,
    ushort* __restrict__ G2swz)
{
    const int idx = blockIdx.x * 256 + threadIdx.x;   // 131072
    const int j = idx & 7, lane = (idx >> 3) & 63, nt = (idx >> 9) & 7, kt = idx >> 12;
    const int k = kt * 32 + (lane >> 4) * 8 + j;
    const int o = nt * 16 + (lane & 15);
    G2swz[idx] = f2b(g_ln[k] * W2[o * 1024 + k]);
}

// ------------------------------------------- Wc0[:, 0:256] in B-frag bf16 layout
__global__ __launch_bounds__(256) void k_wcswz(
    const float* __restrict__ Wc0, ushort* __restrict__ WCB)
{
    const int idx = blockIdx.x * 256 + threadIdx.x;   // 32768
    const int j = idx & 7, lane = (idx >> 3) & 63, nt = (idx >> 9) & 7, ks = idx >> 12;
    const int ic = ks * 32 + (lane >> 4) * 8 + j;
    const int o = nt * 16 + (lane & 15);
    WCB[idx] = f2b(Wc0[o * 512 + ic]);
}

// ------------------------------------------- 3x3 weights [o][ic][ky][kx] -> B-frag bf16
__global__ __launch_bounds__(256) void k_wswz(
    const float* __restrict__ Wr, ushort* __restrict__ WB)
{
    const int idx = blockIdx.x * 256 + threadIdx.x;   // 147456
    const int j = idx & 7, lane = (idx >> 3) & 63, nt = (idx >> 9) & 7;
    const int ks = (idx >> 12) & 3, tap = idx >> 14;
    const int ic = ks * 32 + (lane >> 4) * 8 + j;
    const int o = nt * 16 + (lane & 15);
    WB[idx] = f2b(Wr[o * 1152 + ic * 9 + tap]);
}

// ------------------------------------------- Ai/Bl from feat & Wc0 tails
__global__ __launch_bounds__(128) void k_ab(
    const float* __restrict__ feat, const float* __restrict__ Wc0,
    float* __restrict__ Ai, float* __restrict__ Bl)
{
    __shared__ float fs[128];
    const int r = blockIdx.x, o = threadIdx.x;
    fs[o] = feat[r * 128 + o];
    __syncthreads();
    const float* wa = Wc0 + o * 512 + 256;
    const float* wb = Wc0 + o * 512 + 384;
    float a = 0.f, b = 0.f;
#pragma unroll 4
    for (int c = 0; c < 128; ++c) { float f = fs[c]; a += f * wa[c]; b += f * wb[c]; }
    Ai[r * 128 + o] = a;
    Bl[r * 128 + o] = b;
}

// ------------- outer-product GEMM + per-(i,l) LN stats
__global__ __launch_bounds__(256) void k_outer(
    const ushort* __restrict__ xdT, ushort* __restrict__ Pc,
    float* __restrict__ muArr, float* __restrict__ rstdArr, int ib)
{
    const int tid = threadIdx.x;
    const int w = tid >> 6, lane = tid & 63;
    const int m_w = (w >> 1) << 6;
    const int n_w = (w & 1) << 6;
    const int lo = lane & 15, kg = lane >> 4;
    const int rowA0 = (ib << 5) + (blockIdx.y << 7) + m_w;
    const int rowB0 = (blockIdx.x << 7) + n_w;

    f32x4 acc[4][4] = {};
#pragma unroll
    for (int ks = 0; ks < 2; ++ks) {
        bf16x8 a[4], b[4];
#pragma unroll
        for (int mt = 0; mt < 4; ++mt)
            a[mt] = *(const bf16x8*)&xdT[(rowA0 + mt * 16 + lo) * 64 + ks * 32 + kg * 8];
#pragma unroll
        for (int nt = 0; nt < 4; ++nt)
            b[nt] = *(const bf16x8*)&xdT[(rowB0 + nt * 16 + lo) * 64 + ks * 32 + kg * 8];
#pragma unroll
        for (int mt = 0; mt < 4; ++mt)
#pragma unroll
            for (int nt = 0; nt < 4; ++nt)
                acc[mt][nt] = __builtin_amdgcn_mfma_f32_16x16x32_bf16(a[mt], b[nt], acc[mt][nt], 0, 0, 0);
    }

    const float sc = 1.f / 64.f;
#pragma unroll
    for (int ii = 0; ii < 2; ++ii) {
#pragma unroll
        for (int ll = 0; ll < 2; ++ll) {
            float s = 0.f, q = 0.f;
#pragma unroll
            for (int dm = 0; dm < 2; ++dm)
#pragma unroll
                for (int dn = 0; dn < 2; ++dn)
#pragma unroll
                    for (int r = 0; r < 4; ++r) {
                        const float v = acc[ii * 2 + dm][ll * 2 + dn][r] * sc;
                        s += v; q += v * v;
                    }
#pragma unroll
            for (int off = 1; off < 64; off <<= 1) { s += __shfl_xor(s, off); q += __shfl_xor(q, off); }
            if (lane == 0) {
                const int i_loc = (((blockIdx.y << 7) + m_w) >> 5) + ii;
                const int l = (((blockIdx.x << 7) + n_w) >> 5) + ll;
                const int pixg = ((ib + i_loc) << 8) + l;
                const float mu = s * (1.f / 1024.f);
                const float var = q * (1.f / 1024.f) - mu * mu;
                muArr[pixg] = mu;
                rstdArr[pixg] = rsqrtf(var + 1e-5f);
            }
        }
    }
#pragma unroll
    for (int mt = 0; mt < 4; ++mt) {
        const int mrow = (blockIdx.y << 7) + m_w + mt * 16;
        const int i_loc = mrow >> 5;
        const int p0 = (mrow & 31) + kg * 4;
#pragma unroll
        for (int nt = 0; nt < 4; ++nt) {
            const int ncol = (blockIdx.x << 7) + n_w + nt * 16;
            const int l = ncol >> 5;
            const int q = (ncol & 31) + lo;
            ushort* dst = &Pc[(((i_loc << 8) + l) << 10) + q];
#pragma unroll
            for (int r = 0; r < 4; ++r)
                dst[(p0 + r) << 5] = f2b(acc[mt][nt][r] * sc);
        }
    }
}

// ------------- projection GEMM, LN folded; writes pair2 bf16
__global__ __launch_bounds__(256) void k_proj(
    const ushort* __restrict__ Pc, const ushort* __restrict__ G2swz,
    const float* __restrict__ muArr, const float* __restrict__ rstdArr,
    const float* __restrict__ S1, const float* __restrict__ S2,
    ushort* __restrict__ pair2b, int ib)
{
    const int tid = threadIdx.x;
    const int w = tid >> 6, lane = tid & 63;
    const int m_w = (w >> 1) << 5;
    const int n_w = (w & 1) << 5;
    const int lo = lane & 15, kg = lane >> 4;
    const int row0 = (blockIdx.x << 6) + m_w;
    const int ntg0 = (blockIdx.y << 2) + (n_w >> 4);

    f32x4 acc[2][2] = {};
#pragma unroll 4
    for (int ks = 0; ks < 32; ++ks) {
        bf16x8 a[2], b[2];
#pragma unroll
        for (int mt = 0; mt < 2; ++mt)
            a[mt] = *(const bf16x8*)&Pc[(row0 + mt * 16 + lo) * 1024 + ks * 32 + kg * 8];
#pragma unroll
        for (int nt = 0; nt < 2; ++nt)
            b[nt] = *(const bf16x8*)&G2swz[((ks * 8 + ntg0 + nt) * 64 + lane) * 8];
#pragma unroll
        for (int mt = 0; mt < 2; ++mt)
#pragma unroll
            for (int nt = 0; nt < 2; ++nt)
                acc[mt][nt] = __builtin_amdgcn_mfma_f32_16x16x32_bf16(a[mt], b[nt], acc[mt][nt], 0, 0, 0);
    }
#pragma unroll
    for (int mt = 0; mt < 2; ++mt) {
#pragma unroll
        for (int r = 0; r < 4; ++r) {
            const int pix_loc = row0 + mt * 16 + kg * 4 + r;
            const int pixg = (ib << 8) + pix_loc;
            const float mu = muArr[pixg], rs = rstdArr[pixg];
#pragma unroll
            for (int nt = 0; nt < 2; ++nt) {
                const int o = (blockIdx.y << 6) + n_w + nt * 16 + lo;
                pair2b[pixg * 128 + o] = f2b(rs * (acc[mt][nt][r] - mu * S1[o]) + S2[o]);
            }
        }
    }
}

// ------------- 1x1 conv (MFMA): cat(pairo fp32, pair2B bf16) @ WCB + Ai + Bl, + IN partials
// grid 1024: 64 px/block, 128 o. 4 waves: m_w=(w>>1)*32 px, n_w=(w&1)*64 o.
__global__ __launch_bounds__(256) void k_conv1x1m(
    const float* __restrict__ pairo, const ushort* __restrict__ pair2B,
    const float* __restrict__ Ai, const float* __restrict__ Bl,
    const ushort* __restrict__ WCB, ushort* __restrict__ X0b,
    float* __restrict__ ps, float* __restrict__ pq)
{
    const int tid = threadIdx.x;
    const int w = tid >> 6, lane = tid & 63;
    const int lo = lane & 15, kg = lane >> 4;
    const int m_w = (w >> 1) << 5;
    const int n_w = (w & 1) << 6;
    const int n4 = (w & 1) << 2;
    const int px0 = blockIdx.x << 6;
    const int iu = px0 >> 8;

    f32x4 acc[2][4] = {};
#pragma unroll
    for (int ks = 0; ks < 8; ++ks) {
        const int coff = (ks & 3) * 32 + kg * 8;
        bf16x8 a[2], b[4];
#pragma unroll
        for (int mt = 0; mt < 2; ++mt) {
            const int px = px0 + m_w + mt * 16 + lo;
            if (ks < 4) {
                const float4 f0 = *(const float4*)&pairo[px * 128 + coff];
                const float4 f1 = *(const float4*)&pairo[px * 128 + coff + 4];
                bf16x8 t;
                t[0] = (short)f2b(f0.x); t[1] = (short)f2b(f0.y);
                t[2] = (short)f2b(f0.z); t[3] = (short)f2b(f0.w);
                t[4] = (short)f2b(f1.x); t[5] = (short)f2b(f1.y);
                t[6] = (short)f2b(f1.z); t[7] = (short)f2b(f1.w);
                a[mt] = t;
            } else {
                a[mt] = *(const bf16x8*)&pair2B[px * 128 + coff];
            }
        }
#pragma unroll
        for (int nt = 0; nt < 4; ++nt)
            b[nt] = *(const bf16x8*)&WCB[((ks * 8 + n4 + nt) * 64 + lane) * 8];
#pragma unroll
        for (int mt = 0; mt < 2; ++mt)
#pragma unroll
            for (int nt = 0; nt < 4; ++nt)
                acc[mt][nt] = __builtin_amdgcn_mfma_f32_16x16x32_bf16(a[mt], b[nt], acc[mt][nt], 0, 0, 0);
    }

    float lsum[4] = {0.f, 0.f, 0.f, 0.f}, lsq[4] = {0.f, 0.f, 0.f, 0.f};
#pragma unroll
    for (int nt = 0; nt < 4; ++nt) {
        const int o = n_w + nt * 16 + lo;
        const float aadd = Ai[iu * 128 + o];
#pragma unroll
        for (int mt = 0; mt < 2; ++mt) {
#pragma unroll
            for (int r = 0; r < 4; ++r) {
                const int lpos = (px0 & 255) + m_w + mt * 16 + kg * 4 + r;
                const float v = acc[mt][nt][r] + aadd + Bl[lpos * 128 + o];
                X0b[((px0 + m_w + mt * 16 + kg * 4 + r) << 7) + o] = f2b(v);
                lsum[nt] += v; lsq[nt] += v * v;
            }
        }
    }
#pragma unroll
    for (int nt = 0; nt < 4; ++nt) {
        lsum[nt] += __shfl_xor(lsum[nt], 16); lsum[nt] += __shfl_xor(lsum[nt], 32);
        lsq[nt]  += __shfl_xor(lsq[nt], 16);  lsq[nt]  += __shfl_xor(lsq[nt], 32);
    }
    __shared__ float red_s[4][4][16], red_q[4][4][16];
    if (kg == 0) {
#pragma unroll
        for (int nt = 0; nt < 4; ++nt) { red_s[w][nt][lo] = lsum[nt]; red_q[w][nt][lo] = lsq[nt]; }
    }
    __syncthreads();
    if (tid < 128) {
        const int o = tid;
        const int half = o >> 6, nt = (o & 63) >> 4, lo2 = o & 15;
        const float s = red_s[half][nt][lo2] + red_s[half + 2][nt][lo2];
        const float q = red_q[half][nt][lo2] + red_q[half + 2][nt][lo2];
        ps[blockIdx.x * 128 + o] = s;
        pq[blockIdx.x * 128 + o] = q;
    }
}

// ------------- 3x3 conv (MFMA implicit im2col), branch-free unrolled, o-split.
// grid (4,256,2): x0=bx*64, y=by, oz=bz (64-o half). 4 waves: m_w=(w>>1)*32 px, nq=w&1 (32-o).
__global__ __launch_bounds__(256) void k_conv3x3m(
    const ushort* __restrict__ Xb, const ushort* __restrict__ WB,
    ushort* __restrict__ outb, float* __restrict__ ps, float* __restrict__ pq)
{
    const int tid = threadIdx.x;
    const int w = tid >> 6, lane = tid & 63;
    const int lo = lane & 15, kg = lane >> 4;
    const int m_w = (w >> 1) << 5;
    const int nq = w & 1;
    const int x0 = blockIdx.x << 6;
    const int y = blockIdx.y;
    const int oz = blockIdx.z;
    const int ntb = (oz << 2) + (nq << 1);
    const bf16x8 ZB = {};

    f32x4 acc[2][2] = {};
#pragma unroll
    for (int tap = 0; tap < 9; ++tap) {
        const int ky = tap / 3, kx = tap % 3;
        const int yy = y + ky - 1;
        const bool vy = (unsigned)yy < 256u;
        const int yc = vy ? yy : 0;
        int abase[2]; bool ok[2];
#pragma unroll
        for (int mt = 0; mt < 2; ++mt) {
            const int xx = x0 + m_w + mt * 16 + lo + kx - 1;
            ok[mt] = vy && ((unsigned)xx < 256u);
            const int xc = xx < 0 ? 0 : (xx > 255 ? 255 : xx);
            abase[mt] = (((yc << 8) + xc) << 7) + kg * 8;
        }
#pragma unroll
        for (int ks = 0; ks < 4; ++ks) {
            bf16x8 a[2], b[2];
#pragma unroll
            for (int mt = 0; mt < 2; ++mt) {
                bf16x8 v = *(const bf16x8*)&Xb[abase[mt] + ks * 32];
                a[mt] = ok[mt] ? v : ZB;
            }
#pragma unroll
            for (int nt = 0; nt < 2; ++nt)
                b[nt] = *(const bf16x8*)&WB[(((tap * 4 + ks) * 8 + ntb + nt) * 64 + lane) * 8];
#pragma unroll
            for (int mt = 0; mt < 2; ++mt)
#pragma unroll
                for (int nt = 0; nt < 2; ++nt)
                    acc[mt][nt] = __builtin_amdgcn_mfma_f32_16x16x32_bf16(a[mt], b[nt], acc[mt][nt], 0, 0, 0);
        }
    }

    float lsum[2] = {0.f, 0.f}, lsq[2] = {0.f, 0.f};
#pragma unroll
    for (int nt = 0; nt < 2; ++nt) {
        const int o = (oz << 6) + (nq << 5) + nt * 16 + lo;
#pragma unroll
        for (int mt = 0; mt < 2; ++mt) {
#pragma unroll
            for (int r = 0; r < 4; ++r) {
                const int xo = x0 + m_w + mt * 16 + kg * 4 + r;
                const float v = acc[mt][nt][r];
                outb[(((y << 8) + xo) << 7) + o] = f2b(v);
                lsum[nt] += v; lsq[nt] += v * v;
            }
        }
    }
#pragma unroll
    for (int nt = 0; nt < 2; ++nt) {
        lsum[nt] += __shfl_xor(lsum[nt], 16); lsum[nt] += __shfl_xor(lsum[nt], 32);
        lsq[nt]  += __shfl_xor(lsq[nt], 16);  lsq[nt]  += __shfl_xor(lsq[nt], 32);
    }
    __shared__ float red_s[4][2][16], red_q[4][2][16];
    if (kg == 0) {
#pragma unroll
        for (int nt = 0; nt < 2; ++nt) { red_s[w][nt][lo] = lsum[nt]; red_q[w][nt][lo] = lsq[nt]; }
    }
    __syncthreads();
    if (tid < 64) {
        const int o_loc = tid;
        const int wq = o_loc >> 5, nt = (o_loc >> 4) & 1, lo2 = o_loc & 15;
        const float s = red_s[wq][nt][lo2] + red_s[wq + 2][nt][lo2];
        const float q = red_q[wq][nt][lo2] + red_q[wq + 2][nt][lo2];
        const int blk = (y << 2) + blockIdx.x;
        ps[blk * 128 + (oz << 6) + o_loc] = s;
        pq[blk * 128 + (oz << 6) + o_loc] = q;
    }
}

// ------------------------------------------- per-channel IN params
__global__ __launch_bounds__(256) void k_stats(
    const float* __restrict__ ps, const float* __restrict__ pq, int R,
    const float* __restrict__ g, const float* __restrict__ be,
    float* __restrict__ scl, float* __restrict__ sft)
{
    const int o = blockIdx.x, tid = threadIdx.x;
    float s = 0.f, q = 0.f;
    for (int r = tid; r < R; r += 256) { s += ps[r * 128 + o]; q += pq[r * 128 + o]; }
#pragma unroll
    for (int off = 32; off; off >>= 1) { s += __shfl_down(s, off); q += __shfl_down(q, off); }
    __shared__ float rs[4], rq[4];
    if ((tid & 63) == 0) { rs[tid >> 6] = s; rq[tid >> 6] = q; }
    __syncthreads();
    if (tid == 0) {
        s = rs[0] + rs[1] + rs[2] + rs[3];
        q = rq[0] + rq[1] + rq[2] + rq[3];
        const float mean = s * (1.f / 65536.f);
        const float var = q * (1.f / 65536.f) - mean * mean;
        const float rstd = rsqrtf(var + 1e-6f);
        const float sc = g[o] * rstd;
        scl[o] = sc;
        sft[o] = be[o] - mean * sc;
    }
}

// ------------------------------------------- norm + ELU: bf16 in -> bf16 out (8 ch/thread)
__global__ __launch_bounds__(256) void k_norm_elu(
    const ushort* __restrict__ in, ushort* __restrict__ out,
    const float* __restrict__ scl, const float* __restrict__ sft)
{
    const int j = blockIdx.x * 256 + threadIdx.x;   // 1048576 groups of 8
    const uint4 pv = ((const uint4*)in)[j];
    const ushort* u = (const ushort*)&pv;
    const int o0 = (j & 15) << 3;
    ushort ro[8];
#pragma unroll
    for (int t = 0; t < 8; ++t) {
        const float x = b2f(u[t]);
        ro[t] = f2b(eluf(x * scl[o0 + t] + sft[o0 + t]));
    }
    ((uint4*)out)[j] = *(const uint4*)ro;
}

// ------------------------------------------- final: out = elu(x1 + norm(h2)), fp32 out
__global__ __launch_bounds__(256) void k_final(
    const ushort* __restrict__ x1b, const ushort* __restrict__ h2b,
    const float* __restrict__ scl, const float* __restrict__ sft,
    float* __restrict__ outp)
{
    const int j = blockIdx.x * 256 + threadIdx.x;   // 1048576 groups of 8
    const uint4 xv = ((const uint4*)x1b)[j];
    const uint4 hv = ((const uint4*)h2b)[j];
    const ushort* xu = (const ushort*)&xv;
    const ushort* hu = (const ushort*)&hv;
    const int o0 = (j & 15) << 3;
    float ro[8];
#pragma unroll
    for (int t = 0; t < 8; ++t) {
        const float a = b2f(xu[t]);
        const float h = b2f(hu[t]);
        ro[t] = eluf(a + h * scl[o0 + t] + sft[o0 + t]);
    }
    ((float4*)outp)[2 * j]     = *(const float4*)&ro[0];
    ((float4*)outp)[2 * j + 1] = *(const float4*)&ro[4];
}

extern "C" void kernel_launch(void* const* d_in, const int* in_sizes, int n_in,
                              void* d_out, int out_size, void* d_ws, size_t ws_size,
                              hipStream_t stream)
{
    const float* msa   = (const float*)d_in[0];
    const float* pairo = (const float*)d_in[1];
    const float* W1    = (const float*)d_in[2];
    const float* b1    = (const float*)d_in[3];
    const float* g_ln  = (const float*)d_in[4];
    const float* be_ln = (const float*)d_in[5];
    const float* W2    = (const float*)d_in[6];
    const float* b2    = (const float*)d_in[7];
    const float* Wc0   = (const float*)d_in[8];
    const float* g0    = (const float*)d_in[9];
    const float* be0   = (const float*)d_in[10];
    const float* Wr1   = (const float*)d_in[11];
    const float* g1    = (const float*)d_in[12];
    const float* be1   = (const float*)d_in[13];
    const float* Wr2   = (const float*)d_in[14];
    const float* g2    = (const float*)d_in[15];
    const float* be2   = (const float*)d_in[16];

    float* ws = (float*)d_ws;
    ushort* xdT   = (ushort*)ws;                    // 262144 f
    float* feat   = ws + 262144;                    // 32768
    float* Ai     = ws + 294912;                    // 32768
    float* Bl     = ws + 327680;                    // 32768
    float* S1     = ws + 360448;                    // 128
    float* S2     = ws + 360576;                    // 128
    float* scl    = ws + 360704;                    // 128
    float* sft    = ws + 360832;                    // 128
    ushort* WCB   = (ushort*)(ws + 360960);         // 16384 f
    ushort* G2swz = (ushort*)(ws + 393728);         // 65536 f
    float* muArr  = ws + 459264;                    // 65536
    float* rstdA  = ws + 524800;                    // 65536
    float* ps     = ws + 590336;                    // 524288
    float* pq     = ws + 1114624;                   // 524288
    ushort* WB1   = (ushort*)(ws + 1638912);        // 73728 f
    ushort* WB2   = (ushort*)(ws + 1712640);        // 73728 f
    float* R1     = ws + 1786368;                   // 8388608 f
    float* R2     = ws + 10174976;                  // 8388608 f
    // R1: [first half] pair2B -> X2b ; [second half] X1b
    ushort* pair2B = (ushort*)R1;
    ushort* X2b    = (ushort*)R1;
    ushort* X1b    = (ushort*)(R1 + 4194304);
    // R2: Pc (whole) -> [first half] X0b -> H2b ; [second half] Hb
    ushort* Pc  = (ushort*)R2;
    ushort* X0b = (ushort*)R2;
    ushort* H2b = (ushort*)R2;
    ushort* Hb  = (ushort*)(R2 + 4194304);

    k_xdown<<<dim3(2048), dim3(256), 0, stream>>>(msa, W1, b1, xdT);
    k_feat<<<dim3(128), dim3(256), 0, stream>>>(msa, feat);
    k_g2<<<dim3(128), dim3(256), 0, stream>>>(W2, g_ln, be_ln, b2, S1, S2);
    k_g2swz<<<dim3(512), dim3(256), 0, stream>>>(W2, g_ln, G2swz);
    k_wcswz<<<dim3(128), dim3(256), 0, stream>>>(Wc0, WCB);
    k_ab<<<dim3(256), dim3(128), 0, stream>>>(feat, Wc0, Ai, Bl);
    k_wswz<<<dim3(576), dim3(256), 0, stream>>>(Wr1, WB1);
    k_wswz<<<dim3(576), dim3(256), 0, stream>>>(Wr2, WB2);

    for (int c = 0; c < 4; ++c) {
        const int ib = c * 64;
        k_outer<<<dim3(64, 16), dim3(256), 0, stream>>>(xdT, Pc, muArr, rstdA, ib);
        k_proj<<<dim3(256, 2), dim3(256), 0, stream>>>(Pc, G2swz, muArr, rstdA, S1, S2, pair2B, ib);
    }

    k_conv1x1m<<<dim3(1024), dim3(256), 0, stream>>>(pairo, pair2B, Ai, Bl, WCB, X0b, ps, pq);
    k_stats<<<dim3(128), dim3(256), 0, stream>>>(ps, pq, 1024, g0, be0, scl, sft);
    k_norm_elu<<<dim3(4096), dim3(256), 0, stream>>>(X0b, X1b, scl, sft);

    k_conv3x3m<<<dim3(4, 256, 2), dim3(256), 0, stream>>>(X1b, WB1, Hb, ps, pq);
    k_stats<<<dim3(128), dim3(256), 0, stream>>>(ps, pq, 1024, g1, be1, scl, sft);
    k_norm_elu<<<dim3(4096), dim3(256), 0, stream>>>(Hb, X2b, scl, sft);

    k_conv3x3m<<<dim3(4, 256, 2), dim3(256), 0, stream>>>(X2b, WB2, H2b, ps, pq);
    k_stats<<<dim3(128), dim3(256), 0, stream>>>(ps, pq, 1024, g2, be2, scl, sft);

    k_final<<<dim3(4096), dim3(256), 0, stream>>>(X1b, H2b, scl, sft, (float*)d_out);
}

// Round 5
// 421.696 us; speedup vs baseline: 1.1820x; 1.1820x over previous
//
#include <hip/hip_runtime.h>
#include <hip/hip_bf16.h>
#include <math.h>

// Shapes: B=1, N=64, L=256, nf=64, npj=32, nfo=128
// All GEMM-shaped work on bf16 MFMA (16x16x32). All intermediate activations bf16.
// Fragment conventions (validated rounds 1-3):
//   A-frag: row = lane&15, k = (lane>>4)*8 + j
//   B-frag: col = lane&15, k = (lane>>4)*8 + j
//   C-frag: col = lane&15, row = (lane>>4)*4 + r

typedef __attribute__((ext_vector_type(8))) short bf16x8;
typedef __attribute__((ext_vector_type(4))) float f32x4;

__device__ __forceinline__ float eluf(float x) { return x > 0.f ? x : expm1f(x); }
__device__ __forceinline__ ushort f2b(float f) {
    unsigned u = __float_as_uint(f);
    return (ushort)((u + 0x7fff + ((u >> 16) & 1)) >> 16);
}
__device__ __forceinline__ float b2f(ushort u) {
    return __uint_as_float(((unsigned)u) << 16);
}

// ---------------------------------------------------------------- x_down -> xdT bf16
__global__ __launch_bounds__(256) void k_xdown(
    const float* __restrict__ msa, const float* __restrict__ W1,
    const float* __restrict__ b1, ushort* __restrict__ xdT)
{
    __shared__ float w1s[32 * 65];
    const int tid = threadIdx.x;
    for (int t = tid; t < 2048; t += 256) w1s[(t >> 6) * 65 + (t & 63)] = W1[t];
    __syncthreads();
    const int id = blockIdx.x * 256 + tid;
    const int p = id & 31, l = (id >> 5) & 255, n = id >> 13;
    const float* mrow = msa + (((n << 8) + l) << 6);
    const float* wrow = w1s + p * 65;
    float s = 0.f;
#pragma unroll 8
    for (int f = 0; f < 64; ++f) s += mrow[f] * wrow[f];
    xdT[(((l << 5) + p) << 6) + n] = f2b(s + b1[p]);
}

// ---------------------------------------------------------------- feat_1d
__global__ __launch_bounds__(256) void k_feat(
    const float* __restrict__ msa, float* __restrict__ feat)
{
    const int id = blockIdx.x * 256 + threadIdx.x;   // 32768
    const int c = id & 127, l = id >> 7;
    float v;
    if (c < 64) {
        float s = 0.f;
        for (int n = 0; n < 64; ++n) s += msa[(((n << 8) + l) << 6) + c];
        v = s * (1.f / 64.f);
    } else {
        v = msa[(l << 6) + (c - 64)];
    }
    feat[id] = v;
}

// ------------------------------------------- S1[o]=sum_c g*W2, S2[o]=sum_c be*W2 + b2
__global__ __launch_bounds__(256) void k_g2(
    const float* __restrict__ W2, const float* __restrict__ g_ln,
    const float* __restrict__ be_ln, const float* __restrict__ b2,
    float* __restrict__ S1, float* __restrict__ S2)
{
    const int o = blockIdx.x, tid = threadIdx.x;
    float s1 = 0.f, s2 = 0.f;
    for (int c = tid; c < 1024; c += 256) {
        float w = W2[o * 1024 + c];
        s1 += g_ln[c] * w;
        s2 += be_ln[c] * w;
    }
#pragma unroll
    for (int off = 32; off; off >>= 1) { s1 += __shfl_down(s1, off); s2 += __shfl_down(s2, off); }
    __shared__ float r1[4], r2[4];
    if ((tid & 63) == 0) { r1[tid >> 6] = s1; r2[tid >> 6] = s2; }
    __syncthreads();
    if (tid == 0) {
        S1[o] = r1[0] + r1[1] + r1[2] + r1[3];
        S2[o] = r2[0] + r2[1] + r2[2] + r2[3] + b2[o];
    }
}

// ------------------------------------------- G2 in B-fragment bf16 layout
__global__ __launch_bounds__(256) void k_g2swz(
    const float* __restrict__ W2, const float* __restrict__ g_ln,
    ushort* __restrict__ G2swz)
{
    const int idx = blockIdx.x * 256 + threadIdx.x;   // 131072
    const int j = idx & 7, lane = (idx >> 3) & 63, nt = (idx >> 9) & 7, kt = idx >> 12;
    const int k = kt * 32 + (lane >> 4) * 8 + j;
    const int o = nt * 16 + (lane & 15);
    G2swz[idx] = f2b(g_ln[k] * W2[o * 1024 + k]);
}

// ------------------------------------------- Wc0[:, 0:256] in B-frag bf16 layout; also zero pad buf
__global__ __launch_bounds__(256) void k_wcswz(
    const float* __restrict__ Wc0, ushort* __restrict__ WCB, ushort* __restrict__ zbuf)
{
    const int idx = blockIdx.x * 256 + threadIdx.x;   // 32768
    const int j = idx & 7, lane = (idx >> 3) & 63, nt = (idx >> 9) & 7, ks = idx >> 12;
    const int ic = ks * 32 + (lane >> 4) * 8 + j;
    const int o = nt * 16 + (lane & 15);
    WCB[idx] = f2b(Wc0[o * 512 + ic]);
    if (idx < 128) zbuf[idx] = 0;
}

// ------------------------------------------- 3x3 weights [o][ic][ky][kx] -> B-frag bf16
__global__ __launch_bounds__(256) void k_wswz(
    const float* __restrict__ Wr, ushort* __restrict__ WB)
{
    const int idx = blockIdx.x * 256 + threadIdx.x;   // 147456
    const int j = idx & 7, lane = (idx >> 3) & 63, nt = (idx >> 9) & 7;
    const int ks = (idx >> 12) & 3, tap = idx >> 14;
    const int ic = ks * 32 + (lane >> 4) * 8 + j;
    const int o = nt * 16 + (lane & 15);
    WB[idx] = f2b(Wr[o * 1152 + ic * 9 + tap]);
}

// ------------------------------------------- Ai/Bl from feat & Wc0 tails
__global__ __launch_bounds__(128) void k_ab(
    const float* __restrict__ feat, const float* __restrict__ Wc0,
    float* __restrict__ Ai, float* __restrict__ Bl)
{
    __shared__ float fs[128];
    const int r = blockIdx.x, o = threadIdx.x;
    fs[o] = feat[r * 128 + o];
    __syncthreads();
    const float* wa = Wc0 + o * 512 + 256;
    const float* wb = Wc0 + o * 512 + 384;
    float a = 0.f, b = 0.f;
#pragma unroll 4
    for (int c = 0; c < 128; ++c) { float f = fs[c]; a += f * wa[c]; b += f * wb[c]; }
    Ai[r * 128 + o] = a;
    Bl[r * 128 + o] = b;
}

// ------------- outer-product GEMM + per-(i,l) LN stats
__global__ __launch_bounds__(256) void k_outer(
    const ushort* __restrict__ xdT, ushort* __restrict__ Pc,
    float* __restrict__ muArr, float* __restrict__ rstdArr, int ib)
{
    const int tid = threadIdx.x;
    const int w = tid >> 6, lane = tid & 63;
    const int m_w = (w >> 1) << 6;
    const int n_w = (w & 1) << 6;
    const int lo = lane & 15, kg = lane >> 4;
    const int rowA0 = (ib << 5) + (blockIdx.y << 7) + m_w;
    const int rowB0 = (blockIdx.x << 7) + n_w;

    f32x4 acc[4][4] = {};
#pragma unroll
    for (int ks = 0; ks < 2; ++ks) {
        bf16x8 a[4], b[4];
#pragma unroll
        for (int mt = 0; mt < 4; ++mt)
            a[mt] = *(const bf16x8*)&xdT[(rowA0 + mt * 16 + lo) * 64 + ks * 32 + kg * 8];
#pragma unroll
        for (int nt = 0; nt < 4; ++nt)
            b[nt] = *(const bf16x8*)&xdT[(rowB0 + nt * 16 + lo) * 64 + ks * 32 + kg * 8];
#pragma unroll
        for (int mt = 0; mt < 4; ++mt)
#pragma unroll
            for (int nt = 0; nt < 4; ++nt)
                acc[mt][nt] = __builtin_amdgcn_mfma_f32_16x16x32_bf16(a[mt], b[nt], acc[mt][nt], 0, 0, 0);
    }

    const float sc = 1.f / 64.f;
#pragma unroll
    for (int ii = 0; ii < 2; ++ii) {
#pragma unroll
        for (int ll = 0; ll < 2; ++ll) {
            float s = 0.f, q = 0.f;
#pragma unroll
            for (int dm = 0; dm < 2; ++dm)
#pragma unroll
                for (int dn = 0; dn < 2; ++dn)
#pragma unroll
                    for (int r = 0; r < 4; ++r) {
                        const float v = acc[ii * 2 + dm][ll * 2 + dn][r] * sc;
                        s += v; q += v * v;
                    }
#pragma unroll
            for (int off = 1; off < 64; off <<= 1) { s += __shfl_xor(s, off); q += __shfl_xor(q, off); }
            if (lane == 0) {
                const int i_loc = (((blockIdx.y << 7) + m_w) >> 5) + ii;
                const int l = (((blockIdx.x << 7) + n_w) >> 5) + ll;
                const int pixg = ((ib + i_loc) << 8) + l;
                const float mu = s * (1.f / 1024.f);
                const float var = q * (1.f / 1024.f) - mu * mu;
                muArr[pixg] = mu;
                rstdArr[pixg] = rsqrtf(var + 1e-5f);
            }
        }
    }
#pragma unroll
    for (int mt = 0; mt < 4; ++mt) {
        const int mrow = (blockIdx.y << 7) + m_w + mt * 16;
        const int i_loc = mrow >> 5;
        const int p0 = (mrow & 31) + kg * 4;
#pragma unroll
        for (int nt = 0; nt < 4; ++nt) {
            const int ncol = (blockIdx.x << 7) + n_w + nt * 16;
            const int l = ncol >> 5;
            const int q = (ncol & 31) + lo;
            ushort* dst = &Pc[(((i_loc << 8) + l) << 10) + q];
#pragma unroll
            for (int r = 0; r < 4; ++r)
                dst[(p0 + r) << 5] = f2b(acc[mt][nt][r] * sc);
        }
    }
}

// ------------- projection GEMM, LN folded; writes pair2 bf16
__global__ __launch_bounds__(256) void k_proj(
    const ushort* __restrict__ Pc, const ushort* __restrict__ G2swz,
    const float* __restrict__ muArr, const float* __restrict__ rstdArr,
    const float* __restrict__ S1, const float* __restrict__ S2,
    ushort* __restrict__ pair2b, int ib)
{
    const int tid = threadIdx.x;
    const int w = tid >> 6, lane = tid & 63;
    const int m_w = (w >> 1) << 5;
    const int n_w = (w & 1) << 5;
    const int lo = lane & 15, kg = lane >> 4;
    const int row0 = (blockIdx.x << 6) + m_w;
    const int ntg0 = (blockIdx.y << 2) + (n_w >> 4);

    f32x4 acc[2][2] = {};
#pragma unroll 4
    for (int ks = 0; ks < 32; ++ks) {
        bf16x8 a[2], b[2];
#pragma unroll
        for (int mt = 0; mt < 2; ++mt)
            a[mt] = *(const bf16x8*)&Pc[(row0 + mt * 16 + lo) * 1024 + ks * 32 + kg * 8];
#pragma unroll
        for (int nt = 0; nt < 2; ++nt)
            b[nt] = *(const bf16x8*)&G2swz[((ks * 8 + ntg0 + nt) * 64 + lane) * 8];
#pragma unroll
        for (int mt = 0; mt < 2; ++mt)
#pragma unroll
            for (int nt = 0; nt < 2; ++nt)
                acc[mt][nt] = __builtin_amdgcn_mfma_f32_16x16x32_bf16(a[mt], b[nt], acc[mt][nt], 0, 0, 0);
    }
#pragma unroll
    for (int mt = 0; mt < 2; ++mt) {
#pragma unroll
        for (int r = 0; r < 4; ++r) {
            const int pix_loc = row0 + mt * 16 + kg * 4 + r;
            const int pixg = (ib << 8) + pix_loc;
            const float mu = muArr[pixg], rs = rstdArr[pixg];
#pragma unroll
            for (int nt = 0; nt < 2; ++nt) {
                const int o = (blockIdx.y << 6) + n_w + nt * 16 + lo;
                pair2b[pixg * 128 + o] = f2b(rs * (acc[mt][nt][r] - mu * S1[o]) + S2[o]);
            }
        }
    }
}

// ------------- 1x1 conv (MFMA): cat(pairo fp32, pair2B bf16) @ WCB + Ai + Bl, + IN partials
// grid 1024: 64 px/block, 128 o. 4 waves: m_w=(w>>1)*32 px, n_w=(w&1)*64 o.
__global__ __launch_bounds__(256) void k_conv1x1m(
    const float* __restrict__ pairo, const ushort* __restrict__ pair2B,
    const float* __restrict__ Ai, const float* __restrict__ Bl,
    const ushort* __restrict__ WCB, ushort* __restrict__ X0b,
    float* __restrict__ ps, float* __restrict__ pq)
{
    const int tid = threadIdx.x;
    const int w = tid >> 6, lane = tid & 63;
    const int lo = lane & 15, kg = lane >> 4;
    const int m_w = (w >> 1) << 5;
    const int n_w = (w & 1) << 6;
    const int n4 = (w & 1) << 2;
    const int px0 = blockIdx.x << 6;
    const int iu = px0 >> 8;

    f32x4 acc[2][4] = {};
#pragma unroll
    for (int ks = 0; ks < 8; ++ks) {
        const int coff = (ks & 3) * 32 + kg * 8;
        bf16x8 a[2], b[4];
#pragma unroll
        for (int mt = 0; mt < 2; ++mt) {
            const int px = px0 + m_w + mt * 16 + lo;
            if (ks < 4) {
                const float4 f0 = *(const float4*)&pairo[px * 128 + coff];
                const float4 f1 = *(const float4*)&pairo[px * 128 + coff + 4];
                bf16x8 t;
                t[0] = (short)f2b(f0.x); t[1] = (short)f2b(f0.y);
                t[2] = (short)f2b(f0.z); t[3] = (short)f2b(f0.w);
                t[4] = (short)f2b(f1.x); t[5] = (short)f2b(f1.y);
                t[6] = (short)f2b(f1.z); t[7] = (short)f2b(f1.w);
                a[mt] = t;
            } else {
                a[mt] = *(const bf16x8*)&pair2B[px * 128 + coff];
            }
        }
#pragma unroll
        for (int nt = 0; nt < 4; ++nt)
            b[nt] = *(const bf16x8*)&WCB[((ks * 8 + n4 + nt) * 64 + lane) * 8];
#pragma unroll
        for (int mt = 0; mt < 2; ++mt)
#pragma unroll
            for (int nt = 0; nt < 4; ++nt)
                acc[mt][nt] = __builtin_amdgcn_mfma_f32_16x16x32_bf16(a[mt], b[nt], acc[mt][nt], 0, 0, 0);
    }

    float lsum[4] = {0.f, 0.f, 0.f, 0.f}, lsq[4] = {0.f, 0.f, 0.f, 0.f};
#pragma unroll
    for (int nt = 0; nt < 4; ++nt) {
        const int o = n_w + nt * 16 + lo;
        const float aadd = Ai[iu * 128 + o];
#pragma unroll
        for (int mt = 0; mt < 2; ++mt) {
#pragma unroll
            for (int r = 0; r < 4; ++r) {
                const int lpos = (px0 & 255) + m_w + mt * 16 + kg * 4 + r;
                const float v = acc[mt][nt][r] + aadd + Bl[lpos * 128 + o];
                X0b[((px0 + m_w + mt * 16 + kg * 4 + r) << 7) + o] = f2b(v);
                lsum[nt] += v; lsq[nt] += v * v;
            }
        }
    }
#pragma unroll
    for (int nt = 0; nt < 4; ++nt) {
        lsum[nt] += __shfl_xor(lsum[nt], 16); lsum[nt] += __shfl_xor(lsum[nt], 32);
        lsq[nt]  += __shfl_xor(lsq[nt], 16);  lsq[nt]  += __shfl_xor(lsq[nt], 32);
    }
    __shared__ float red_s[4][4][16], red_q[4][4][16];
    if (kg == 0) {
#pragma unroll
        for (int nt = 0; nt < 4; ++nt) { red_s[w][nt][lo] = lsum[nt]; red_q[w][nt][lo] = lsq[nt]; }
    }
    __syncthreads();
    if (tid < 128) {
        const int o = tid;
        const int half = o >> 6, nt = (o & 63) >> 4, lo2 = o & 15;
        const float s = red_s[half][nt][lo2] + red_s[half + 2][nt][lo2];
        const float q = red_q[half][nt][lo2] + red_q[half + 2][nt][lo2];
        ps[blockIdx.x * 128 + o] = s;
        pq[blockIdx.x * 128 + o] = q;
    }
}

// ------------- 3x3 conv (MFMA implicit im2col), mt=4 x nt=4, zero-page OOB.
// grid (2,256): x0=bx*128, y=by. 4 waves: m_w=(w>>1)*64 px, n_w=(w&1)*64 o.
__global__ __launch_bounds__(256) void k_conv3x3m(
    const ushort* __restrict__ Xb, const ushort* __restrict__ WB,
    const ushort* __restrict__ zbuf,
    ushort* __restrict__ outb, float* __restrict__ ps, float* __restrict__ pq)
{
    const int tid = threadIdx.x;
    const int w = tid >> 6, lane = tid & 63;
    const int lo = lane & 15, kg = lane >> 4;
    const int m_w = (w >> 1) << 6;
    const int n_w = (w & 1) << 6;
    const int n4 = (w & 1) << 2;
    const int x0 = blockIdx.x << 7;
    const int y = blockIdx.y;

    f32x4 acc[4][4] = {};
#pragma unroll
    for (int tap = 0; tap < 9; ++tap) {
        const int ky = tap / 3, kx = tap % 3;
        const int yy = y + ky - 1;
        const bool vy = (unsigned)yy < 256u;
        const int yc = vy ? yy : 0;
        const ushort* aptr[4];
#pragma unroll
        for (int mt = 0; mt < 4; ++mt) {
            const int xx = x0 + m_w + mt * 16 + lo + kx - 1;
            const bool ok = vy && ((unsigned)xx < 256u);
            const int xc = xx < 0 ? 0 : (xx > 255 ? 255 : xx);
            aptr[mt] = ok ? &Xb[(((yc << 8) + xc) << 7) + kg * 8] : &zbuf[kg * 8];
        }
#pragma unroll
        for (int ks = 0; ks < 4; ++ks) {
            bf16x8 a[4], b[4];
#pragma unroll
            for (int mt = 0; mt < 4; ++mt)
                a[mt] = *(const bf16x8*)(aptr[mt] + ks * 32);
#pragma unroll
            for (int nt = 0; nt < 4; ++nt)
                b[nt] = *(const bf16x8*)&WB[(((tap * 4 + ks) * 8 + n4 + nt) * 64 + lane) * 8];
#pragma unroll
            for (int mt = 0; mt < 4; ++mt)
#pragma unroll
                for (int nt = 0; nt < 4; ++nt)
                    acc[mt][nt] = __builtin_amdgcn_mfma_f32_16x16x32_bf16(a[mt], b[nt], acc[mt][nt], 0, 0, 0);
        }
    }

    float lsum[4] = {0.f, 0.f, 0.f, 0.f}, lsq[4] = {0.f, 0.f, 0.f, 0.f};
#pragma unroll
    for (int nt = 0; nt < 4; ++nt) {
        const int o = n_w + nt * 16 + lo;
#pragma unroll
        for (int mt = 0; mt < 4; ++mt) {
#pragma unroll
            for (int r = 0; r < 4; ++r) {
                const int xo = x0 + m_w + mt * 16 + kg * 4 + r;
                const float v = acc[mt][nt][r];
                outb[(((y << 8) + xo) << 7) + o] = f2b(v);
                lsum[nt] += v; lsq[nt] += v * v;
            }
        }
    }
#pragma unroll
    for (int nt = 0; nt < 4; ++nt) {
        lsum[nt] += __shfl_xor(lsum[nt], 16); lsum[nt] += __shfl_xor(lsum[nt], 32);
        lsq[nt]  += __shfl_xor(lsq[nt], 16);  lsq[nt]  += __shfl_xor(lsq[nt], 32);
    }
    __shared__ float red_s[4][4][16], red_q[4][4][16];
    if (kg == 0) {
#pragma unroll
        for (int nt = 0; nt < 4; ++nt) { red_s[w][nt][lo] = lsum[nt]; red_q[w][nt][lo] = lsq[nt]; }
    }
    __syncthreads();
    if (tid < 128) {
        const int o = tid;
        const int half = o >> 6, nt = (o & 63) >> 4, lo2 = o & 15;
        const float s = red_s[half][nt][lo2] + red_s[half + 2][nt][lo2];
        const float q = red_q[half][nt][lo2] + red_q[half + 2][nt][lo2];
        const int blk = (y << 1) + blockIdx.x;
        ps[blk * 128 + o] = s;
        pq[blk * 128 + o] = q;
    }
}

// ------------------------------------------- per-channel IN params
__global__ __launch_bounds__(256) void k_stats(
    const float* __restrict__ ps, const float* __restrict__ pq, int R,
    const float* __restrict__ g, const float* __restrict__ be,
    float* __restrict__ scl, float* __restrict__ sft)
{
    const int o = blockIdx.x, tid = threadIdx.x;
    float s = 0.f, q = 0.f;
    for (int r = tid; r < R; r += 256) { s += ps[r * 128 + o]; q += pq[r * 128 + o]; }
#pragma unroll
    for (int off = 32; off; off >>= 1) { s += __shfl_down(s, off); q += __shfl_down(q, off); }
    __shared__ float rs[4], rq[4];
    if ((tid & 63) == 0) { rs[tid >> 6] = s; rq[tid >> 6] = q; }
    __syncthreads();
    if (tid == 0) {
        s = rs[0] + rs[1] + rs[2] + rs[3];
        q = rq[0] + rq[1] + rq[2] + rq[3];
        const float mean = s * (1.f / 65536.f);
        const float var = q * (1.f / 65536.f) - mean * mean;
        const float rstd = rsqrtf(var + 1e-6f);
        const float sc = g[o] * rstd;
        scl[o] = sc;
        sft[o] = be[o] - mean * sc;
    }
}

// ------------------------------------------- norm + ELU: bf16 in -> bf16 out (8 ch/thread)
__global__ __launch_bounds__(256) void k_norm_elu(
    const ushort* __restrict__ in, ushort* __restrict__ out,
    const float* __restrict__ scl, const float* __restrict__ sft)
{
    const int j = blockIdx.x * 256 + threadIdx.x;   // 1048576 groups of 8
    const uint4 pv = ((const uint4*)in)[j];
    const ushort* u = (const ushort*)&pv;
    const int o0 = (j & 15) << 3;
    ushort ro[8];
#pragma unroll
    for (int t = 0; t < 8; ++t) {
        const float x = b2f(u[t]);
        ro[t] = f2b(eluf(x * scl[o0 + t] + sft[o0 + t]));
    }
    ((uint4*)out)[j] = *(const uint4*)ro;
}

// ------------------------------------------- final: out = elu(x1 + norm(h2)), fp32 out
__global__ __launch_bounds__(256) void k_final(
    const ushort* __restrict__ x1b, const ushort* __restrict__ h2b,
    const float* __restrict__ scl, const float* __restrict__ sft,
    float* __restrict__ outp)
{
    const int j = blockIdx.x * 256 + threadIdx.x;   // 1048576 groups of 8
    const uint4 xv = ((const uint4*)x1b)[j];
    const uint4 hv = ((const uint4*)h2b)[j];
    const ushort* xu = (const ushort*)&xv;
    const ushort* hu = (const ushort*)&hv;
    const int o0 = (j & 15) << 3;
    float ro[8];
#pragma unroll
    for (int t = 0; t < 8; ++t) {
        const float a = b2f(xu[t]);
        const float h = b2f(hu[t]);
        ro[t] = eluf(a + h * scl[o0 + t] + sft[o0 + t]);
    }
    ((float4*)outp)[2 * j]     = *(const float4*)&ro[0];
    ((float4*)outp)[2 * j + 1] = *(const float4*)&ro[4];
}

extern "C" void kernel_launch(void* const* d_in, const int* in_sizes, int n_in,
                              void* d_out, int out_size, void* d_ws, size_t ws_size,
                              hipStream_t stream)
{
    const float* msa   = (const float*)d_in[0];
    const float* pairo = (const float*)d_in[1];
    const float* W1    = (const float*)d_in[2];
    const float* b1    = (const float*)d_in[3];
    const float* g_ln  = (const float*)d_in[4];
    const float* be_ln = (const float*)d_in[5];
    const float* W2    = (const float*)d_in[6];
    const float* b2    = (const float*)d_in[7];
    const float* Wc0   = (const float*)d_in[8];
    const float* g0    = (const float*)d_in[9];
    const float* be0   = (const float*)d_in[10];
    const float* Wr1   = (const float*)d_in[11];
    const float* g1    = (const float*)d_in[12];
    const float* be1   = (const float*)d_in[13];
    const float* Wr2   = (const float*)d_in[14];
    const float* g2    = (const float*)d_in[15];
    const float* be2   = (const float*)d_in[16];

    float* ws = (float*)d_ws;
    ushort* xdT   = (ushort*)ws;                    // 262144 f
    float* feat   = ws + 262144;                    // 32768
    float* Ai     = ws + 294912;                    // 32768
    float* Bl     = ws + 327680;                    // 32768
    float* S1     = ws + 360448;                    // 128
    float* S2     = ws + 360576;                    // 128
    float* scl    = ws + 360704;                    // 128
    float* sft    = ws + 360832;                    // 128
    ushort* WCB   = (ushort*)(ws + 360960);         // 16384 f
    ushort* zbuf  = (ushort*)(ws + 377344);         // 128 f (256 bf16 zeros)
    ushort* G2swz = (ushort*)(ws + 393728);         // 65536 f
    float* muArr  = ws + 459264;                    // 65536
    float* rstdA  = ws + 524800;                    // 65536
    float* ps     = ws + 590336;                    // 524288
    float* pq     = ws + 1114624;                   // 524288
    ushort* WB1   = (ushort*)(ws + 1638912);        // 73728 f
    ushort* WB2   = (ushort*)(ws + 1712640);        // 73728 f
    float* R1     = ws + 1786368;                   // 8388608 f
    float* R2     = ws + 10174976;                  // 8388608 f
    // R1: [first half] pair2B -> X2b ; [second half] X1b
    ushort* pair2B = (ushort*)R1;
    ushort* X2b    = (ushort*)R1;
    ushort* X1b    = (ushort*)(R1 + 4194304);
    // R2: Pc (whole) -> [first half] X0b -> H2b ; [second half] Hb
    ushort* Pc  = (ushort*)R2;
    ushort* X0b = (ushort*)R2;
    ushort* H2b = (ushort*)R2;
    ushort* Hb  = (ushort*)(R2 + 4194304);

    k_xdown<<<dim3(2048), dim3(256), 0, stream>>>(msa, W1, b1, xdT);
    k_feat<<<dim3(128), dim3(256), 0, stream>>>(msa, feat);
    k_g2<<<dim3(128), dim3(256), 0, stream>>>(W2, g_ln, be_ln, b2, S1, S2);
    k_g2swz<<<dim3(512), dim3(256), 0, stream>>>(W2, g_ln, G2swz);
    k_wcswz<<<dim3(128), dim3(256), 0, stream>>>(Wc0, WCB, zbuf);
    k_ab<<<dim3(256), dim3(128), 0, stream>>>(feat, Wc0, Ai, Bl);
    k_wswz<<<dim3(576), dim3(256), 0, stream>>>(Wr1, WB1);
    k_wswz<<<dim3(576), dim3(256), 0, stream>>>(Wr2, WB2);

    for (int c = 0; c < 4; ++c) {
        const int ib = c * 64;
        k_outer<<<dim3(64, 16), dim3(256), 0, stream>>>(xdT, Pc, muArr, rstdA, ib);
        k_proj<<<dim3(256, 2), dim3(256), 0, stream>>>(Pc, G2swz, muArr, rstdA, S1, S2, pair2B, ib);
    }

    k_conv1x1m<<<dim3(1024), dim3(256), 0, stream>>>(pairo, pair2B, Ai, Bl, WCB, X0b, ps, pq);
    k_stats<<<dim3(128), dim3(256), 0, stream>>>(ps, pq, 1024, g0, be0, scl, sft);
    k_norm_elu<<<dim3(4096), dim3(256), 0, stream>>>(X0b, X1b, scl, sft);

    k_conv3x3m<<<dim3(2, 256), dim3(256), 0, stream>>>(X1b, WB1, zbuf, Hb, ps, pq);
    k_stats<<<dim3(128), dim3(256), 0, stream>>>(ps, pq, 512, g1, be1, scl, sft);
    k_norm_elu<<<dim3(4096), dim3(256), 0, stream>>>(Hb, X2b, scl, sft);

    k_conv3x3m<<<dim3(2, 256), dim3(256), 0, stream>>>(X2b, WB2, zbuf, H2b, ps, pq);
    k_stats<<<dim3(128), dim3(256), 0, stream>>>(ps, pq, 512, g2, be2, scl, sft);

    k_final<<<dim3(4096), dim3(256), 0, stream>>>(X1b, H2b, scl, sft, (float*)d_out);
}

// Round 6
// 328.429 us; speedup vs baseline: 1.5177x; 1.2840x over previous
//
#include <hip/hip_runtime.h>
#include <hip/hip_bf16.h>
#include <math.h>

// Shapes: B=1, N=64, L=256, nf=64, npj=32, nfo=128
// All GEMM-shaped work on bf16 MFMA (16x16x32). All intermediate activations bf16.
// Fragment conventions (validated rounds 1-5):
//   A-frag: row = lane&15, k = (lane>>4)*8 + j
//   B-frag: col = lane&15, k = (lane>>4)*8 + j
//   C-frag: col = lane&15, row = (lane>>4)*4 + r

typedef __attribute__((ext_vector_type(8))) short bf16x8;
typedef __attribute__((ext_vector_type(4))) float f32x4;

__device__ __forceinline__ float eluf(float x) { return x > 0.f ? x : expm1f(x); }
__device__ __forceinline__ ushort f2b(float f) {
    unsigned u = __float_as_uint(f);
    return (ushort)((u + 0x7fff + ((u >> 16) & 1)) >> 16);
}
__device__ __forceinline__ float b2f(ushort u) {
    return __uint_as_float(((unsigned)u) << 16);
}

// ================================================================ mega-prologue
// blocks: [0,2048) xdown | [2048,2176) g2 | [2176,2688) g2swz | [2688,2816) wcswz
//         [2816,3072) ab | [3072,3648) wswz1 | [3648,4224) wswz2
__global__ __launch_bounds__(256) void k_prep(
    const float* __restrict__ msa, const float* __restrict__ W1,
    const float* __restrict__ b1, ushort* __restrict__ xdT,
    const float* __restrict__ W2, const float* __restrict__ g_ln,
    const float* __restrict__ be_ln, const float* __restrict__ b2,
    float* __restrict__ S1, float* __restrict__ S2, ushort* __restrict__ G2swz,
    const float* __restrict__ Wc0, ushort* __restrict__ WCB, ushort* __restrict__ zbuf,
    float* __restrict__ Ai, float* __restrict__ Bl,
    const float* __restrict__ Wr1, ushort* __restrict__ WB1,
    const float* __restrict__ Wr2, ushort* __restrict__ WB2)
{
    __shared__ float smem[32 * 65];
    const int b = blockIdx.x, tid = threadIdx.x;
    if (b < 2048) {
        // ---- x_down -> xdT bf16
        for (int t = tid; t < 2048; t += 256) smem[(t >> 6) * 65 + (t & 63)] = W1[t];
        __syncthreads();
        const int id = b * 256 + tid;
        const int p = id & 31, l = (id >> 5) & 255, n = id >> 13;
        const float* mrow = msa + (((n << 8) + l) << 6);
        const float* wrow = smem + p * 65;
        float s = 0.f;
#pragma unroll 8
        for (int f = 0; f < 64; ++f) s += mrow[f] * wrow[f];
        xdT[(((l << 5) + p) << 6) + n] = f2b(s + b1[p]);
    } else if (b < 2176) {
        // ---- S1/S2
        const int o = b - 2048;
        float s1 = 0.f, s2 = 0.f;
        for (int c = tid; c < 1024; c += 256) {
            float w = W2[o * 1024 + c];
            s1 += g_ln[c] * w;
            s2 += be_ln[c] * w;
        }
#pragma unroll
        for (int off = 32; off; off >>= 1) { s1 += __shfl_down(s1, off); s2 += __shfl_down(s2, off); }
        __shared__ float r1[4], r2[4];
        if ((tid & 63) == 0) { r1[tid >> 6] = s1; r2[tid >> 6] = s2; }
        __syncthreads();
        if (tid == 0) {
            S1[o] = r1[0] + r1[1] + r1[2] + r1[3];
            S2[o] = r2[0] + r2[1] + r2[2] + r2[3] + b2[o];
        }
    } else if (b < 2688) {
        // ---- G2 B-frag layout
        const int idx = (b - 2176) * 256 + tid;   // 131072
        const int j = idx & 7, lane = (idx >> 3) & 63, nt = (idx >> 9) & 7, kt = idx >> 12;
        const int k = kt * 32 + (lane >> 4) * 8 + j;
        const int o = nt * 16 + (lane & 15);
        G2swz[idx] = f2b(g_ln[k] * W2[o * 1024 + k]);
    } else if (b < 2816) {
        // ---- Wc0[:,0:256] B-frag + zero buffer
        const int idx = (b - 2688) * 256 + tid;   // 32768
        const int j = idx & 7, lane = (idx >> 3) & 63, nt = (idx >> 9) & 7, ks = idx >> 12;
        const int ic = ks * 32 + (lane >> 4) * 8 + j;
        const int o = nt * 16 + (lane & 15);
        WCB[idx] = f2b(Wc0[o * 512 + ic]);
        if (idx < 128) zbuf[idx] = 0;
    } else if (b < 3072) {
        // ---- feat row + Ai/Bl
        const int r = b - 2816;
        if (tid < 128) {
            const int c = tid;
            float v;
            if (c < 64) {
                float s = 0.f;
                for (int n = 0; n < 64; ++n) s += msa[(((n << 8) + r) << 6) + c];
                v = s * (1.f / 64.f);
            } else {
                v = msa[(r << 6) + (c - 64)];
            }
            smem[c] = v;
        }
        __syncthreads();
        const int o = tid & 127, half = tid >> 7;
        const float* wv = Wc0 + o * 512 + 256 + (half << 7);
        float a = 0.f;
#pragma unroll 4
        for (int c = 0; c < 128; ++c) a += smem[c] * wv[c];
        (half ? Bl : Ai)[r * 128 + o] = a;
    } else if (b < 3648) {
        const int idx = (b - 3072) * 256 + tid;   // 147456
        const int j = idx & 7, lane = (idx >> 3) & 63, nt = (idx >> 9) & 7;
        const int ks = (idx >> 12) & 3, tap = idx >> 14;
        const int ic = ks * 32 + (lane >> 4) * 8 + j;
        const int o = nt * 16 + (lane & 15);
        WB1[idx] = f2b(Wr1[o * 1152 + ic * 9 + tap]);
    } else {
        const int idx = (b - 3648) * 256 + tid;   // 147456
        const int j = idx & 7, lane = (idx >> 3) & 63, nt = (idx >> 9) & 7;
        const int ks = (idx >> 12) & 3, tap = idx >> 14;
        const int ic = ks * 32 + (lane >> 4) * 8 + j;
        const int o = nt * 16 + (lane & 15);
        WB2[idx] = f2b(Wr2[o * 1152 + ic * 9 + tap]);
    }
}

// ================================================================ fused pair path
// grid (64,64): by = i-block (4 i), bx = l-block (4 l). 16 px/block.
// Phase 1 (outer GEMM 128x128, K=64) -> LN stats -> P to LDS (bf16, XOR-swizzled)
// Phase 2 (proj GEMM 16px x 128o, K=1024 from LDS) -> LN-folded epilogue -> pair2 bf16
__global__ __launch_bounds__(256) void k_pairf(
    const ushort* __restrict__ xdT, const ushort* __restrict__ G2swz,
    const float* __restrict__ S1, const float* __restrict__ S2,
    ushort* __restrict__ pair2b)
{
    __shared__ ushort P_lds[16 * 1024];   // 32 KB; byte off = px*2048 + ((ch*2) ^ ((px&7)<<4))
    __shared__ float mus[16], rstds[16];
    const int tid = threadIdx.x;
    const int w = tid >> 6, lane = tid & 63;
    const int lo = lane & 15, kg = lane >> 4;
    const int m_w = (w >> 1) << 6;
    const int n_w = (w & 1) << 6;
    const int rowA0 = (blockIdx.y << 7) + m_w;
    const int rowB0 = (blockIdx.x << 7) + n_w;

    f32x4 acc[4][4] = {};
#pragma unroll
    for (int ks = 0; ks < 2; ++ks) {
        bf16x8 a[4], b[4];
#pragma unroll
        for (int mt = 0; mt < 4; ++mt)
            a[mt] = *(const bf16x8*)&xdT[(rowA0 + mt * 16 + lo) * 64 + ks * 32 + kg * 8];
#pragma unroll
        for (int nt = 0; nt < 4; ++nt)
            b[nt] = *(const bf16x8*)&xdT[(rowB0 + nt * 16 + lo) * 64 + ks * 32 + kg * 8];
#pragma unroll
        for (int mt = 0; mt < 4; ++mt)
#pragma unroll
            for (int nt = 0; nt < 4; ++nt)
                acc[mt][nt] = __builtin_amdgcn_mfma_f32_16x16x32_bf16(a[mt], b[nt], acc[mt][nt], 0, 0, 0);
    }

    const float sc = 1.f / 64.f;
    // LN stats for the wave's 4 pixels (each 32x32 pq block fully in-wave)
#pragma unroll
    for (int ii = 0; ii < 2; ++ii) {
#pragma unroll
        for (int ll = 0; ll < 2; ++ll) {
            float s = 0.f, q = 0.f;
#pragma unroll
            for (int dm = 0; dm < 2; ++dm)
#pragma unroll
                for (int dn = 0; dn < 2; ++dn)
#pragma unroll
                    for (int r = 0; r < 4; ++r) {
                        const float v = acc[ii * 2 + dm][ll * 2 + dn][r] * sc;
                        s += v; q += v * v;
                    }
#pragma unroll
            for (int off = 1; off < 64; off <<= 1) { s += __shfl_xor(s, off); q += __shfl_xor(q, off); }
            if (lane == 0) {
                const int px = ((w >> 1) * 2 + ii) * 4 + ((w & 1) * 2 + ll);
                const float mu = s * (1.f / 1024.f);
                const float var = q * (1.f / 1024.f) - mu * mu;
                mus[px] = mu;
                rstds[px] = rsqrtf(var + 1e-5f);
            }
        }
    }
    // P -> LDS (bf16, swizzled)
#pragma unroll
    for (int mt = 0; mt < 4; ++mt) {
        const int mrow = m_w + mt * 16;
        const int i_loc = mrow >> 5;
        const int p0 = (mrow & 31) + kg * 4;
#pragma unroll
        for (int nt = 0; nt < 4; ++nt) {
            const int ncol = n_w + nt * 16;
            const int l_loc = ncol >> 5;
            const int q = (ncol & 31) + lo;
            const int px = i_loc * 4 + l_loc;
            char* base = (char*)P_lds + px * 2048;
#pragma unroll
            for (int r = 0; r < 4; ++r) {
                const int ch = (p0 + r) * 32 + q;
                *(ushort*)(base + ((ch * 2) ^ ((px & 7) << 4))) = f2b(acc[mt][nt][r] * sc);
            }
        }
    }
    __syncthreads();

    // proj: wave w handles o-tiles {2w, 2w+1}; A rows = 16 px from LDS
    f32x4 pacc[2] = {};
    const int xsw = (lo & 7) << 4;
#pragma unroll 4
    for (int ks = 0; ks < 32; ++ks) {
        const bf16x8 a = *(const bf16x8*)((const char*)P_lds + lo * 2048 + (((ks * 32 + kg * 8) * 2) ^ xsw));
        bf16x8 b0 = *(const bf16x8*)&G2swz[((ks * 8 + (w << 1) + 0) * 64 + lane) * 8];
        bf16x8 b1 = *(const bf16x8*)&G2swz[((ks * 8 + (w << 1) + 1) * 64 + lane) * 8];
        pacc[0] = __builtin_amdgcn_mfma_f32_16x16x32_bf16(a, b0, pacc[0], 0, 0, 0);
        pacc[1] = __builtin_amdgcn_mfma_f32_16x16x32_bf16(a, b1, pacc[1], 0, 0, 0);
    }
#pragma unroll
    for (int nt = 0; nt < 2; ++nt) {
        const int o = (w << 5) + nt * 16 + lo;
        const float s1v = S1[o], s2v = S2[o];
#pragma unroll
        for (int r = 0; r < 4; ++r) {
            const int px = kg * 4 + r;
            const int i = (blockIdx.y << 2) + (px >> 2);
            const int l = (blockIdx.x << 2) + (px & 3);
            pair2b[(((i << 8) + l) << 7) + o] = f2b(rstds[px] * (pacc[nt][r] - mus[px] * s1v) + s2v);
        }
    }
}

// ------------- 1x1 conv (MFMA): cat(pairo fp32, pair2B bf16) @ WCB + Ai + Bl, + IN partials
__global__ __launch_bounds__(256) void k_conv1x1m(
    const float* __restrict__ pairo, const ushort* __restrict__ pair2B,
    const float* __restrict__ Ai, const float* __restrict__ Bl,
    const ushort* __restrict__ WCB, ushort* __restrict__ X0b,
    float* __restrict__ ps, float* __restrict__ pq)
{
    const int tid = threadIdx.x;
    const int w = tid >> 6, lane = tid & 63;
    const int lo = lane & 15, kg = lane >> 4;
    const int m_w = (w >> 1) << 5;
    const int n_w = (w & 1) << 6;
    const int n4 = (w & 1) << 2;
    const int px0 = blockIdx.x << 6;
    const int iu = px0 >> 8;

    f32x4 acc[2][4] = {};
#pragma unroll
    for (int ks = 0; ks < 8; ++ks) {
        const int coff = (ks & 3) * 32 + kg * 8;
        bf16x8 a[2], b[4];
#pragma unroll
        for (int mt = 0; mt < 2; ++mt) {
            const int px = px0 + m_w + mt * 16 + lo;
            if (ks < 4) {
                const float4 f0 = *(const float4*)&pairo[px * 128 + coff];
                const float4 f1 = *(const float4*)&pairo[px * 128 + coff + 4];
                bf16x8 t;
                t[0] = (short)f2b(f0.x); t[1] = (short)f2b(f0.y);
                t[2] = (short)f2b(f0.z); t[3] = (short)f2b(f0.w);
                t[4] = (short)f2b(f1.x); t[5] = (short)f2b(f1.y);
                t[6] = (short)f2b(f1.z); t[7] = (short)f2b(f1.w);
                a[mt] = t;
            } else {
                a[mt] = *(const bf16x8*)&pair2B[px * 128 + coff];
            }
        }
#pragma unroll
        for (int nt = 0; nt < 4; ++nt)
            b[nt] = *(const bf16x8*)&WCB[((ks * 8 + n4 + nt) * 64 + lane) * 8];
#pragma unroll
        for (int mt = 0; mt < 2; ++mt)
#pragma unroll
            for (int nt = 0; nt < 4; ++nt)
                acc[mt][nt] = __builtin_amdgcn_mfma_f32_16x16x32_bf16(a[mt], b[nt], acc[mt][nt], 0, 0, 0);
    }

    float lsum[4] = {0.f, 0.f, 0.f, 0.f}, lsq[4] = {0.f, 0.f, 0.f, 0.f};
#pragma unroll
    for (int nt = 0; nt < 4; ++nt) {
        const int o = n_w + nt * 16 + lo;
        const float aadd = Ai[iu * 128 + o];
#pragma unroll
        for (int mt = 0; mt < 2; ++mt) {
#pragma unroll
            for (int r = 0; r < 4; ++r) {
                const int lpos = (px0 & 255) + m_w + mt * 16 + kg * 4 + r;
                const float v = acc[mt][nt][r] + aadd + Bl[lpos * 128 + o];
                X0b[((px0 + m_w + mt * 16 + kg * 4 + r) << 7) + o] = f2b(v);
                lsum[nt] += v; lsq[nt] += v * v;
            }
        }
    }
#pragma unroll
    for (int nt = 0; nt < 4; ++nt) {
        lsum[nt] += __shfl_xor(lsum[nt], 16); lsum[nt] += __shfl_xor(lsum[nt], 32);
        lsq[nt]  += __shfl_xor(lsq[nt], 16);  lsq[nt]  += __shfl_xor(lsq[nt], 32);
    }
    __shared__ float red_s[4][4][16], red_q[4][4][16];
    if (kg == 0) {
#pragma unroll
        for (int nt = 0; nt < 4; ++nt) { red_s[w][nt][lo] = lsum[nt]; red_q[w][nt][lo] = lsq[nt]; }
    }
    __syncthreads();
    if (tid < 128) {
        const int o = tid;
        const int half = o >> 6, nt = (o & 63) >> 4, lo2 = o & 15;
        const float s = red_s[half][nt][lo2] + red_s[half + 2][nt][lo2];
        const float q = red_q[half][nt][lo2] + red_q[half + 2][nt][lo2];
        ps[blockIdx.x * 128 + o] = s;
        pq[blockIdx.x * 128 + o] = q;
    }
}

// ------------- 3x3 conv (MFMA implicit im2col), 3-stage software pipeline.
// grid (2,256): x0=bx*128, y=by. 4 waves: m_w=(w>>1)*64 px, n_w=(w&1)*64 o.
__global__ __launch_bounds__(256, 2) void k_conv3x3m(
    const ushort* __restrict__ Xb, const ushort* __restrict__ WB,
    const ushort* __restrict__ zbuf,
    ushort* __restrict__ outb, float* __restrict__ ps, float* __restrict__ pq)
{
    const int tid = threadIdx.x;
    const int w = tid >> 6, lane = tid & 63;
    const int lo = lane & 15, kg = lane >> 4;
    const int m_w = (w >> 1) << 6;
    const int n_w = (w & 1) << 6;
    const int n4 = (w & 1) << 2;
    const int x0 = blockIdx.x << 7;
    const int y = blockIdx.y;
    const int zoff = (int)(zbuf - Xb) + kg * 8;

    // all 36 A-offsets in registers (zero-page OOB -> branch-free loads)
    int offs[9][4];
#pragma unroll
    for (int tap = 0; tap < 9; ++tap) {
        const int ky = tap / 3, kx = tap % 3;
        const int yy = y + ky - 1;
        const bool vy = (unsigned)yy < 256u;
        const int yc = vy ? yy : 0;
#pragma unroll
        for (int mt = 0; mt < 4; ++mt) {
            const int xx = x0 + m_w + mt * 16 + lo + kx - 1;
            const bool ok = vy && ((unsigned)xx < 256u);
            const int xc = xx < 0 ? 0 : (xx > 255 ? 255 : xx);
            offs[tap][mt] = ok ? ((((yc << 8) + xc) << 7) + kg * 8) : zoff;
        }
    }

    f32x4 acc[4][4] = {};
    bf16x8 A[3][4], B[3][4];

#define LOADS(S, SL)                                                              \
    {                                                                             \
        const int tap_ = (S) >> 2, ks_ = (S) & 3;                                 \
        _Pragma("unroll")                                                         \
        for (int mt = 0; mt < 4; ++mt)                                            \
            A[SL][mt] = *(const bf16x8*)&Xb[offs[tap_][mt] + ks_ * 32];           \
        _Pragma("unroll")                                                         \
        for (int nt = 0; nt < 4; ++nt)                                            \
            B[SL][nt] = *(const bf16x8*)&WB[(S) * 4096 + (n4 + nt) * 512 + lane * 8]; \
    }
#define MMAS(SL)                                                                  \
    {                                                                             \
        _Pragma("unroll")                                                         \
        for (int mt = 0; mt < 4; ++mt)                                            \
            _Pragma("unroll")                                                     \
            for (int nt = 0; nt < 4; ++nt)                                        \
                acc[mt][nt] = __builtin_amdgcn_mfma_f32_16x16x32_bf16(A[SL][mt], B[SL][nt], acc[mt][nt], 0, 0, 0); \
    }

    LOADS(0, 0);
    LOADS(1, 1);
#pragma unroll
    for (int s = 0; s < 36; ++s) {
        if (s + 2 < 36) {
            LOADS(s + 2, (s + 2) % 3);
        }
        MMAS(s % 3);
    }
#undef LOADS
#undef MMAS

    float lsum[4] = {0.f, 0.f, 0.f, 0.f}, lsq[4] = {0.f, 0.f, 0.f, 0.f};
#pragma unroll
    for (int nt = 0; nt < 4; ++nt) {
        const int o = n_w + nt * 16 + lo;
#pragma unroll
        for (int mt = 0; mt < 4; ++mt) {
#pragma unroll
            for (int r = 0; r < 4; ++r) {
                const int xo = x0 + m_w + mt * 16 + kg * 4 + r;
                const float v = acc[mt][nt][r];
                outb[(((y << 8) + xo) << 7) + o] = f2b(v);
                lsum[nt] += v; lsq[nt] += v * v;
            }
        }
    }
#pragma unroll
    for (int nt = 0; nt < 4; ++nt) {
        lsum[nt] += __shfl_xor(lsum[nt], 16); lsum[nt] += __shfl_xor(lsum[nt], 32);
        lsq[nt]  += __shfl_xor(lsq[nt], 16);  lsq[nt]  += __shfl_xor(lsq[nt], 32);
    }
    __shared__ float red_s[4][4][16], red_q[4][4][16];
    if (kg == 0) {
#pragma unroll
        for (int nt = 0; nt < 4; ++nt) { red_s[w][nt][lo] = lsum[nt]; red_q[w][nt][lo] = lsq[nt]; }
    }
    __syncthreads();
    if (tid < 128) {
        const int o = tid;
        const int half = o >> 6, nt = (o & 63) >> 4, lo2 = o & 15;
        const float s = red_s[half][nt][lo2] + red_s[half + 2][nt][lo2];
        const float q = red_q[half][nt][lo2] + red_q[half + 2][nt][lo2];
        const int blk = (y << 1) + blockIdx.x;
        ps[blk * 128 + o] = s;
        pq[blk * 128 + o] = q;
    }
}

// ------------------------------------------- per-channel IN params
__global__ __launch_bounds__(256) void k_stats(
    const float* __restrict__ ps, const float* __restrict__ pq, int R,
    const float* __restrict__ g, const float* __restrict__ be,
    float* __restrict__ scl, float* __restrict__ sft)
{
    const int o = blockIdx.x, tid = threadIdx.x;
    float s = 0.f, q = 0.f;
    for (int r = tid; r < R; r += 256) { s += ps[r * 128 + o]; q += pq[r * 128 + o]; }
#pragma unroll
    for (int off = 32; off; off >>= 1) { s += __shfl_down(s, off); q += __shfl_down(q, off); }
    __shared__ float rs[4], rq[4];
    if ((tid & 63) == 0) { rs[tid >> 6] = s; rq[tid >> 6] = q; }
    __syncthreads();
    if (tid == 0) {
        s = rs[0] + rs[1] + rs[2] + rs[3];
        q = rq[0] + rq[1] + rq[2] + rq[3];
        const float mean = s * (1.f / 65536.f);
        const float var = q * (1.f / 65536.f) - mean * mean;
        const float rstd = rsqrtf(var + 1e-6f);
        const float sc = g[o] * rstd;
        scl[o] = sc;
        sft[o] = be[o] - mean * sc;
    }
}

// ------------------------------------------- norm + ELU: bf16 in -> bf16 out (8 ch/thread)
__global__ __launch_bounds__(256) void k_norm_elu(
    const ushort* __restrict__ in, ushort* __restrict__ out,
    const float* __restrict__ scl, const float* __restrict__ sft)
{
    const int j = blockIdx.x * 256 + threadIdx.x;   // 1048576 groups of 8
    const uint4 pv = ((const uint4*)in)[j];
    const ushort* u = (const ushort*)&pv;
    const int o0 = (j & 15) << 3;
    ushort ro[8];
#pragma unroll
    for (int t = 0; t < 8; ++t) {
        const float x = b2f(u[t]);
        ro[t] = f2b(eluf(x * scl[o0 + t] + sft[o0 + t]));
    }
    ((uint4*)out)[j] = *(const uint4*)ro;
}

// ------------------------------------------- final: out = elu(x1 + norm(h2)), fp32 out
__global__ __launch_bounds__(256) void k_final(
    const ushort* __restrict__ x1b, const ushort* __restrict__ h2b,
    const float* __restrict__ scl, const float* __restrict__ sft,
    float* __restrict__ outp)
{
    const int j = blockIdx.x * 256 + threadIdx.x;   // 1048576 groups of 8
    const uint4 xv = ((const uint4*)x1b)[j];
    const uint4 hv = ((const uint4*)h2b)[j];
    const ushort* xu = (const ushort*)&xv;
    const ushort* hu = (const ushort*)&hv;
    const int o0 = (j & 15) << 3;
    float ro[8];
#pragma unroll
    for (int t = 0; t < 8; ++t) {
        const float a = b2f(xu[t]);
        const float h = b2f(hu[t]);
        ro[t] = eluf(a + h * scl[o0 + t] + sft[o0 + t]);
    }
    ((float4*)outp)[2 * j]     = *(const float4*)&ro[0];
    ((float4*)outp)[2 * j + 1] = *(const float4*)&ro[4];
}

extern "C" void kernel_launch(void* const* d_in, const int* in_sizes, int n_in,
                              void* d_out, int out_size, void* d_ws, size_t ws_size,
                              hipStream_t stream)
{
    const float* msa   = (const float*)d_in[0];
    const float* pairo = (const float*)d_in[1];
    const float* W1    = (const float*)d_in[2];
    const float* b1    = (const float*)d_in[3];
    const float* g_ln  = (const float*)d_in[4];
    const float* be_ln = (const float*)d_in[5];
    const float* W2    = (const float*)d_in[6];
    const float* b2    = (const float*)d_in[7];
    const float* Wc0   = (const float*)d_in[8];
    const float* g0    = (const float*)d_in[9];
    const float* be0   = (const float*)d_in[10];
    const float* Wr1   = (const float*)d_in[11];
    const float* g1    = (const float*)d_in[12];
    const float* be1   = (const float*)d_in[13];
    const float* Wr2   = (const float*)d_in[14];
    const float* g2    = (const float*)d_in[15];
    const float* be2   = (const float*)d_in[16];

    float* ws = (float*)d_ws;
    ushort* xdT   = (ushort*)ws;                    // 262144 f
    float* Ai     = ws + 294912;                    // 32768
    float* Bl     = ws + 327680;                    // 32768
    float* S1     = ws + 360448;                    // 128
    float* S2     = ws + 360576;                    // 128
    float* scl    = ws + 360704;                    // 128
    float* sft    = ws + 360832;                    // 128
    ushort* WCB   = (ushort*)(ws + 360960);         // 16384 f
    ushort* zbuf  = (ushort*)(ws + 377344);         // 128 f (256 bf16 zeros)
    ushort* G2swz = (ushort*)(ws + 393728);         // 65536 f
    float* ps     = ws + 590336;                    // 524288
    float* pq     = ws + 1114624;                   // 524288
    ushort* WB1   = (ushort*)(ws + 1638912);        // 73728 f
    ushort* WB2   = (ushort*)(ws + 1712640);        // 73728 f
    float* R1     = ws + 1786368;                   // 8388608 f
    float* R2     = ws + 10174976;                  // 8388608 f
    // R1: [first half] pair2B -> X2b ; [second half] X1b
    ushort* pair2B = (ushort*)R1;
    ushort* X2b    = (ushort*)R1;
    ushort* X1b    = (ushort*)(R1 + 4194304);
    // R2: [first half] X0b -> H2b ; [second half] Hb
    ushort* X0b = (ushort*)R2;
    ushort* H2b = (ushort*)R2;
    ushort* Hb  = (ushort*)(R2 + 4194304);

    k_prep<<<dim3(4224), dim3(256), 0, stream>>>(
        msa, W1, b1, xdT, W2, g_ln, be_ln, b2, S1, S2, G2swz,
        Wc0, WCB, zbuf, Ai, Bl, Wr1, WB1, Wr2, WB2);

    k_pairf<<<dim3(64, 64), dim3(256), 0, stream>>>(xdT, G2swz, S1, S2, pair2B);

    k_conv1x1m<<<dim3(1024), dim3(256), 0, stream>>>(pairo, pair2B, Ai, Bl, WCB, X0b, ps, pq);
    k_stats<<<dim3(128), dim3(256), 0, stream>>>(ps, pq, 1024, g0, be0, scl, sft);
    k_norm_elu<<<dim3(4096), dim3(256), 0, stream>>>(X0b, X1b, scl, sft);

    k_conv3x3m<<<dim3(2, 256), dim3(256), 0, stream>>>(X1b, WB1, zbuf, Hb, ps, pq);
    k_stats<<<dim3(128), dim3(256), 0, stream>>>(ps, pq, 512, g1, be1, scl, sft);
    k_norm_elu<<<dim3(4096), dim3(256), 0, stream>>>(Hb, X2b, scl, sft);

    k_conv3x3m<<<dim3(2, 256), dim3(256), 0, stream>>>(X2b, WB2, zbuf, H2b, ps, pq);
    k_stats<<<dim3(128), dim3(256), 0, stream>>>(ps, pq, 512, g2, be2, scl, sft);

    k_final<<<dim3(4096), dim3(256), 0, stream>>>(X1b, H2b, scl, sft, (float*)d_out);
}

// Round 7
// 309.996 us; speedup vs baseline: 1.6080x; 1.0595x over previous
//
#include <hip/hip_runtime.h>
#include <hip/hip_bf16.h>
#include <math.h>

// Shapes: B=1, N=64, L=256, nf=64, npj=32, nfo=128
// All GEMM-shaped work on bf16 MFMA (16x16x32). All intermediate activations bf16.
// Fragment conventions (validated rounds 1-6):
//   A-frag: row = lane&15, k = (lane>>4)*8 + j
//   B-frag: col = lane&15, k = (lane>>4)*8 + j
//   C-frag: col = lane&15, row = (lane>>4)*4 + r

typedef __attribute__((ext_vector_type(8))) short bf16x8;
typedef __attribute__((ext_vector_type(4))) float f32x4;

__device__ __forceinline__ float eluf(float x) { return x > 0.f ? x : expm1f(x); }
__device__ __forceinline__ ushort f2b(float f) {
    unsigned u = __float_as_uint(f);
    return (ushort)((u + 0x7fff + ((u >> 16) & 1)) >> 16);
}
__device__ __forceinline__ float b2f(ushort u) {
    return __uint_as_float(((unsigned)u) << 16);
}

// ================================================================ mega-prologue
// blocks: [0,2048) xdown | [2048,2176) g2 | [2176,2688) g2swz | [2688,2816) wcswz
//         [2816,3072) ab | [3072,3648) wswz1 | [3648,4224) wswz2
__global__ __launch_bounds__(256) void k_prep(
    const float* __restrict__ msa, const float* __restrict__ W1,
    const float* __restrict__ b1, ushort* __restrict__ xdT,
    const float* __restrict__ W2, const float* __restrict__ g_ln,
    const float* __restrict__ be_ln, const float* __restrict__ b2,
    float* __restrict__ S1, float* __restrict__ S2, ushort* __restrict__ G2swz,
    const float* __restrict__ Wc0, ushort* __restrict__ WCB, ushort* __restrict__ zbuf,
    float* __restrict__ Ai, float* __restrict__ Bl,
    const float* __restrict__ Wr1, ushort* __restrict__ WB1,
    const float* __restrict__ Wr2, ushort* __restrict__ WB2)
{
    __shared__ float smem[32 * 65];
    const int b = blockIdx.x, tid = threadIdx.x;
    if (b < 2048) {
        for (int t = tid; t < 2048; t += 256) smem[(t >> 6) * 65 + (t & 63)] = W1[t];
        __syncthreads();
        const int id = b * 256 + tid;
        const int p = id & 31, l = (id >> 5) & 255, n = id >> 13;
        const float* mrow = msa + (((n << 8) + l) << 6);
        const float* wrow = smem + p * 65;
        float s = 0.f;
#pragma unroll 8
        for (int f = 0; f < 64; ++f) s += mrow[f] * wrow[f];
        xdT[(((l << 5) + p) << 6) + n] = f2b(s + b1[p]);
    } else if (b < 2176) {
        const int o = b - 2048;
        float s1 = 0.f, s2 = 0.f;
        for (int c = tid; c < 1024; c += 256) {
            float w = W2[o * 1024 + c];
            s1 += g_ln[c] * w;
            s2 += be_ln[c] * w;
        }
#pragma unroll
        for (int off = 32; off; off >>= 1) { s1 += __shfl_down(s1, off); s2 += __shfl_down(s2, off); }
        __shared__ float r1[4], r2[4];
        if ((tid & 63) == 0) { r1[tid >> 6] = s1; r2[tid >> 6] = s2; }
        __syncthreads();
        if (tid == 0) {
            S1[o] = r1[0] + r1[1] + r1[2] + r1[3];
            S2[o] = r2[0] + r2[1] + r2[2] + r2[3] + b2[o];
        }
    } else if (b < 2688) {
        const int idx = (b - 2176) * 256 + tid;   // 131072
        const int j = idx & 7, lane = (idx >> 3) & 63, nt = (idx >> 9) & 7, kt = idx >> 12;
        const int k = kt * 32 + (lane >> 4) * 8 + j;
        const int o = nt * 16 + (lane & 15);
        G2swz[idx] = f2b(g_ln[k] * W2[o * 1024 + k]);
    } else if (b < 2816) {
        const int idx = (b - 2688) * 256 + tid;   // 32768
        const int j = idx & 7, lane = (idx >> 3) & 63, nt = (idx >> 9) & 7, ks = idx >> 12;
        const int ic = ks * 32 + (lane >> 4) * 8 + j;
        const int o = nt * 16 + (lane & 15);
        WCB[idx] = f2b(Wc0[o * 512 + ic]);
        if (idx < 128) zbuf[idx] = 0;
    } else if (b < 3072) {
        const int r = b - 2816;
        if (tid < 128) {
            const int c = tid;
            float v;
            if (c < 64) {
                float s = 0.f;
                for (int n = 0; n < 64; ++n) s += msa[(((n << 8) + r) << 6) + c];
                v = s * (1.f / 64.f);
            } else {
                v = msa[(r << 6) + (c - 64)];
            }
            smem[c] = v;
        }
        __syncthreads();
        const int o = tid & 127, half = tid >> 7;
        const float* wv = Wc0 + o * 512 + 256 + (half << 7);
        float a = 0.f;
#pragma unroll 4
        for (int c = 0; c < 128; ++c) a += smem[c] * wv[c];
        (half ? Bl : Ai)[r * 128 + o] = a;
    } else if (b < 3648) {
        const int idx = (b - 3072) * 256 + tid;   // 147456
        const int j = idx & 7, lane = (idx >> 3) & 63, nt = (idx >> 9) & 7;
        const int ks = (idx >> 12) & 3, tap = idx >> 14;
        const int ic = ks * 32 + (lane >> 4) * 8 + j;
        const int o = nt * 16 + (lane & 15);
        WB1[idx] = f2b(Wr1[o * 1152 + ic * 9 + tap]);
    } else {
        const int idx = (b - 3648) * 256 + tid;   // 147456
        const int j = idx & 7, lane = (idx >> 3) & 63, nt = (idx >> 9) & 7;
        const int ks = (idx >> 12) & 3, tap = idx >> 14;
        const int ic = ks * 32 + (lane >> 4) * 8 + j;
        const int o = nt * 16 + (lane & 15);
        WB2[idx] = f2b(Wr2[o * 1152 + ic * 9 + tap]);
    }
}

// ================================================================ fused pair path v2
// grid (32,64): bx = l-block (8 l), by = i-block (4 i) -> 32 px/block.
// Phase 1: outer GEMM, M=(l,q)=256 rows, N=(i,p)=128 cols, K=64. Operands swapped so
//          C rows are q -> lane's r=0..3 are consecutive channels -> b64 packed store.
// LDS layout: phys = px*2048 + (L ^ ((px&7)<<4) ^ (((L>>8)&3)<<4)), L = (p*32+q)*2.
//   write: 16 even word-starts x 4 lanes = all 32 banks -> optimal
//   read (L'=ks*64+kg*16): quad = kg^(lo&7), 8 lanes/quad -> conflict-free b128
// Phase 2: proj GEMM M=32px, N=128o, K=1024 from LDS; LN folded in epilogue.
__global__ __launch_bounds__(256, 2) void k_pairf(
    const ushort* __restrict__ xdT, const ushort* __restrict__ G2swz,
    const float* __restrict__ S1, const float* __restrict__ S2,
    ushort* __restrict__ pair2b)
{
    __shared__ ushort P_lds[32 * 1024];   // 64 KB
    __shared__ float mus[32], rstds[32];
    const int tid = threadIdx.x;
    const int w = tid >> 6, lane = tid & 63;
    const int lo = lane & 15, kg = lane >> 4;
    const int lb = blockIdx.x << 3;      // 8 l
    const int ib = blockIdx.y << 2;      // 4 i
    const int m_w = (w >> 1) << 7;       // M half (128 rows of (l,q))
    const int n_w = (w & 1) << 6;        // N half (64 cols of (i,p))

    f32x4 acc[8][4] = {};
#pragma unroll
    for (int ks = 0; ks < 2; ++ks) {
        bf16x8 a[8], b[4];
#pragma unroll
        for (int mt = 0; mt < 8; ++mt)
            a[mt] = *(const bf16x8*)&xdT[((lb << 5) + m_w + mt * 16 + lo) * 64 + ks * 32 + kg * 8];
#pragma unroll
        for (int nt = 0; nt < 4; ++nt)
            b[nt] = *(const bf16x8*)&xdT[((ib << 5) + n_w + nt * 16 + lo) * 64 + ks * 32 + kg * 8];
#pragma unroll
        for (int mt = 0; mt < 8; ++mt)
#pragma unroll
            for (int nt = 0; nt < 4; ++nt)
                acc[mt][nt] = __builtin_amdgcn_mfma_f32_16x16x32_bf16(a[mt], b[nt], acc[mt][nt], 0, 0, 0);
    }

    const float sc = 1.f / 64.f;
    // LN stats: wave covers 8 px = 4 l_loc (mt>>1) x 2 i_loc (nt>>1)
#pragma unroll
    for (int jj = 0; jj < 2; ++jj) {
#pragma unroll
        for (int ii = 0; ii < 4; ++ii) {
            float s = 0.f, q = 0.f;
#pragma unroll
            for (int dm = 0; dm < 2; ++dm)
#pragma unroll
                for (int dn = 0; dn < 2; ++dn)
#pragma unroll
                    for (int r = 0; r < 4; ++r) {
                        const float v = acc[ii * 2 + dm][jj * 2 + dn][r] * sc;
                        s += v; q += v * v;
                    }
#pragma unroll
            for (int off = 1; off < 64; off <<= 1) { s += __shfl_xor(s, off); q += __shfl_xor(q, off); }
            if (lane == 0) {
                const int l_loc = ((w >> 1) << 2) + ii;
                const int i_loc = ((w & 1) << 1) + jj;
                const int px = (i_loc << 3) + l_loc;
                const float mu = s * (1.f / 1024.f);
                const float var = q * (1.f / 1024.f) - mu * mu;
                mus[px] = mu;
                rstds[px] = rsqrtf(var + 1e-5f);
            }
        }
    }
    // P -> LDS: b64 packed (4 consecutive channels per lane)
#pragma unroll
    for (int mt = 0; mt < 8; ++mt) {
        const int mrow = m_w + mt * 16;
        const int l_loc = mrow >> 5;
        const int qb = (mrow & 31) + (kg << 2);
#pragma unroll
        for (int nt = 0; nt < 4; ++nt) {
            const int ncol = n_w + nt * 16;
            const int i_loc = ncol >> 5;
            const int p = (ncol & 31) + lo;
            const int px = (i_loc << 3) + l_loc;
            const int L = (p << 6) + (qb << 1);
            const int phys = (px << 11) + (L ^ ((px & 7) << 4) ^ (((L >> 8) & 3) << 4));
            ushort4 pk;
            pk.x = f2b(acc[mt][nt][0] * sc);
            pk.y = f2b(acc[mt][nt][1] * sc);
            pk.z = f2b(acc[mt][nt][2] * sc);
            pk.w = f2b(acc[mt][nt][3] * sc);
            *(ushort4*)((char*)P_lds + phys) = pk;
        }
    }
    __syncthreads();

    // Phase 2: wave w -> o-tiles {2w, 2w+1}, m-tiles {0,1} (px 0-15, 16-31)
    f32x4 pacc[2][2] = {};
#pragma unroll 4
    for (int ks = 0; ks < 32; ++ks) {
        const int L0 = (ks << 6) + (kg << 4);
        const int off0 = (L0 ^ ((lo & 7) << 4) ^ (((L0 >> 8) & 3) << 4));
        const bf16x8 a0 = *(const bf16x8*)((const char*)P_lds + (lo << 11) + off0);
        const bf16x8 a1 = *(const bf16x8*)((const char*)P_lds + ((16 + lo) << 11) + off0);
        const bf16x8 b0 = *(const bf16x8*)&G2swz[(((ks << 3) + (w << 1) + 0) * 64 + lane) * 8];
        const bf16x8 b1 = *(const bf16x8*)&G2swz[(((ks << 3) + (w << 1) + 1) * 64 + lane) * 8];
        pacc[0][0] = __builtin_amdgcn_mfma_f32_16x16x32_bf16(a0, b0, pacc[0][0], 0, 0, 0);
        pacc[0][1] = __builtin_amdgcn_mfma_f32_16x16x32_bf16(a0, b1, pacc[0][1], 0, 0, 0);
        pacc[1][0] = __builtin_amdgcn_mfma_f32_16x16x32_bf16(a1, b0, pacc[1][0], 0, 0, 0);
        pacc[1][1] = __builtin_amdgcn_mfma_f32_16x16x32_bf16(a1, b1, pacc[1][1], 0, 0, 0);
    }
#pragma unroll
    for (int mt2 = 0; mt2 < 2; ++mt2) {
#pragma unroll
        for (int j = 0; j < 2; ++j) {
            const int o = (((w << 1) + j) << 4) + lo;
            const float s1v = S1[o], s2v = S2[o];
#pragma unroll
            for (int r = 0; r < 4; ++r) {
                const int px = (mt2 << 4) + (kg << 2) + r;
                const int i = ib + (px >> 3), l = lb + (px & 7);
                pair2b[(((i << 8) + l) << 7) + o] = f2b(rstds[px] * (pacc[mt2][j][r] - mus[px] * s1v) + s2v);
            }
        }
    }
}

// ------------- 1x1 conv (MFMA): cat(pairo fp32, pair2B bf16) @ WCB + Ai + Bl, + IN partials
__global__ __launch_bounds__(256) void k_conv1x1m(
    const float* __restrict__ pairo, const ushort* __restrict__ pair2B,
    const float* __restrict__ Ai, const float* __restrict__ Bl,
    const ushort* __restrict__ WCB, ushort* __restrict__ X0b,
    float* __restrict__ ps, float* __restrict__ pq)
{
    const int tid = threadIdx.x;
    const int w = tid >> 6, lane = tid & 63;
    const int lo = lane & 15, kg = lane >> 4;
    const int m_w = (w >> 1) << 5;
    const int n_w = (w & 1) << 6;
    const int n4 = (w & 1) << 2;
    const int px0 = blockIdx.x << 6;
    const int iu = px0 >> 8;

    f32x4 acc[2][4] = {};
#pragma unroll
    for (int ks = 0; ks < 8; ++ks) {
        const int coff = (ks & 3) * 32 + kg * 8;
        bf16x8 a[2], b[4];
#pragma unroll
        for (int mt = 0; mt < 2; ++mt) {
            const int px = px0 + m_w + mt * 16 + lo;
            if (ks < 4) {
                const float4 f0 = *(const float4*)&pairo[px * 128 + coff];
                const float4 f1 = *(const float4*)&pairo[px * 128 + coff + 4];
                bf16x8 t;
                t[0] = (short)f2b(f0.x); t[1] = (short)f2b(f0.y);
                t[2] = (short)f2b(f0.z); t[3] = (short)f2b(f0.w);
                t[4] = (short)f2b(f1.x); t[5] = (short)f2b(f1.y);
                t[6] = (short)f2b(f1.z); t[7] = (short)f2b(f1.w);
                a[mt] = t;
            } else {
                a[mt] = *(const bf16x8*)&pair2B[px * 128 + coff];
            }
        }
#pragma unroll
        for (int nt = 0; nt < 4; ++nt)
            b[nt] = *(const bf16x8*)&WCB[((ks * 8 + n4 + nt) * 64 + lane) * 8];
#pragma unroll
        for (int mt = 0; mt < 2; ++mt)
#pragma unroll
            for (int nt = 0; nt < 4; ++nt)
                acc[mt][nt] = __builtin_amdgcn_mfma_f32_16x16x32_bf16(a[mt], b[nt], acc[mt][nt], 0, 0, 0);
    }

    float lsum[4] = {0.f, 0.f, 0.f, 0.f}, lsq[4] = {0.f, 0.f, 0.f, 0.f};
#pragma unroll
    for (int nt = 0; nt < 4; ++nt) {
        const int o = n_w + nt * 16 + lo;
        const float aadd = Ai[iu * 128 + o];
#pragma unroll
        for (int mt = 0; mt < 2; ++mt) {
#pragma unroll
            for (int r = 0; r < 4; ++r) {
                const int lpos = (px0 & 255) + m_w + mt * 16 + kg * 4 + r;
                const float v = acc[mt][nt][r] + aadd + Bl[lpos * 128 + o];
                X0b[((px0 + m_w + mt * 16 + kg * 4 + r) << 7) + o] = f2b(v);
                lsum[nt] += v; lsq[nt] += v * v;
            }
        }
    }
#pragma unroll
    for (int nt = 0; nt < 4; ++nt) {
        lsum[nt] += __shfl_xor(lsum[nt], 16); lsum[nt] += __shfl_xor(lsum[nt], 32);
        lsq[nt]  += __shfl_xor(lsq[nt], 16);  lsq[nt]  += __shfl_xor(lsq[nt], 32);
    }
    __shared__ float red_s[4][4][16], red_q[4][4][16];
    if (kg == 0) {
#pragma unroll
        for (int nt = 0; nt < 4; ++nt) { red_s[w][nt][lo] = lsum[nt]; red_q[w][nt][lo] = lsq[nt]; }
    }
    __syncthreads();
    if (tid < 128) {
        const int o = tid;
        const int half = o >> 6, nt = (o & 63) >> 4, lo2 = o & 15;
        const float s = red_s[half][nt][lo2] + red_s[half + 2][nt][lo2];
        const float q = red_q[half][nt][lo2] + red_q[half + 2][nt][lo2];
        ps[blockIdx.x * 128 + o] = s;
        pq[blockIdx.x * 128 + o] = q;
    }
}

// ------------- 3x3 conv (MFMA implicit im2col), 3-stage software pipeline.
// grid (2,256): x0=bx*128, y=by. 4 waves: m_w=(w>>1)*64 px, n_w=(w&1)*64 o.
__global__ __launch_bounds__(256, 2) void k_conv3x3m(
    const ushort* __restrict__ Xb, const ushort* __restrict__ WB,
    const ushort* __restrict__ zbuf,
    ushort* __restrict__ outb, float* __restrict__ ps, float* __restrict__ pq)
{
    const int tid = threadIdx.x;
    const int w = tid >> 6, lane = tid & 63;
    const int lo = lane & 15, kg = lane >> 4;
    const int m_w = (w >> 1) << 6;
    const int n_w = (w & 1) << 6;
    const int n4 = (w & 1) << 2;
    const int x0 = blockIdx.x << 7;
    const int y = blockIdx.y;
    const int zoff = (int)(zbuf - Xb) + kg * 8;

    int offs[9][4];
#pragma unroll
    for (int tap = 0; tap < 9; ++tap) {
        const int ky = tap / 3, kx = tap % 3;
        const int yy = y + ky - 1;
        const bool vy = (unsigned)yy < 256u;
        const int yc = vy ? yy : 0;
#pragma unroll
        for (int mt = 0; mt < 4; ++mt) {
            const int xx = x0 + m_w + mt * 16 + lo + kx - 1;
            const bool ok = vy && ((unsigned)xx < 256u);
            const int xc = xx < 0 ? 0 : (xx > 255 ? 255 : xx);
            offs[tap][mt] = ok ? ((((yc << 8) + xc) << 7) + kg * 8) : zoff;
        }
    }

    f32x4 acc[4][4] = {};
    bf16x8 A[3][4], B[3][4];

#define LOADS(S, SL)                                                              \
    {                                                                             \
        const int tap_ = (S) >> 2, ks_ = (S) & 3;                                 \
        _Pragma("unroll")                                                         \
        for (int mt = 0; mt < 4; ++mt)                                            \
            A[SL][mt] = *(const bf16x8*)&Xb[offs[tap_][mt] + ks_ * 32];           \
        _Pragma("unroll")                                                         \
        for (int nt = 0; nt < 4; ++nt)                                            \
            B[SL][nt] = *(const bf16x8*)&WB[(S) * 4096 + (n4 + nt) * 512 + lane * 8]; \
    }
#define MMAS(SL)                                                                  \
    {                                                                             \
        _Pragma("unroll")                                                         \
        for (int mt = 0; mt < 4; ++mt)                                            \
            _Pragma("unroll")                                                     \
            for (int nt = 0; nt < 4; ++nt)                                        \
                acc[mt][nt] = __builtin_amdgcn_mfma_f32_16x16x32_bf16(A[SL][mt], B[SL][nt], acc[mt][nt], 0, 0, 0); \
    }

    LOADS(0, 0);
    LOADS(1, 1);
#pragma unroll
    for (int s = 0; s < 36; ++s) {
        if (s + 2 < 36) {
            LOADS(s + 2, (s + 2) % 3);
        }
        MMAS(s % 3);
    }
#undef LOADS
#undef MMAS

    float lsum[4] = {0.f, 0.f, 0.f, 0.f}, lsq[4] = {0.f, 0.f, 0.f, 0.f};
#pragma unroll
    for (int nt = 0; nt < 4; ++nt) {
        const int o = n_w + nt * 16 + lo;
#pragma unroll
        for (int mt = 0; mt < 4; ++mt) {
#pragma unroll
            for (int r = 0; r < 4; ++r) {
                const int xo = x0 + m_w + mt * 16 + kg * 4 + r;
                const float v = acc[mt][nt][r];
                outb[(((y << 8) + xo) << 7) + o] = f2b(v);
                lsum[nt] += v; lsq[nt] += v * v;
            }
        }
    }
#pragma unroll
    for (int nt = 0; nt < 4; ++nt) {
        lsum[nt] += __shfl_xor(lsum[nt], 16); lsum[nt] += __shfl_xor(lsum[nt], 32);
        lsq[nt]  += __shfl_xor(lsq[nt], 16);  lsq[nt]  += __shfl_xor(lsq[nt], 32);
    }
    __shared__ float red_s[4][4][16], red_q[4][4][16];
    if (kg == 0) {
#pragma unroll
        for (int nt = 0; nt < 4; ++nt) { red_s[w][nt][lo] = lsum[nt]; red_q[w][nt][lo] = lsq[nt]; }
    }
    __syncthreads();
    if (tid < 128) {
        const int o = tid;
        const int half = o >> 6, nt = (o & 63) >> 4, lo2 = o & 15;
        const float s = red_s[half][nt][lo2] + red_s[half + 2][nt][lo2];
        const float q = red_q[half][nt][lo2] + red_q[half + 2][nt][lo2];
        const int blk = (y << 1) + blockIdx.x;
        ps[blk * 128 + o] = s;
        pq[blk * 128 + o] = q;
    }
}

// ------------------------------------------- per-channel IN params
__global__ __launch_bounds__(256) void k_stats(
    const float* __restrict__ ps, const float* __restrict__ pq, int R,
    const float* __restrict__ g, const float* __restrict__ be,
    float* __restrict__ scl, float* __restrict__ sft)
{
    const int o = blockIdx.x, tid = threadIdx.x;
    float s = 0.f, q = 0.f;
    for (int r = tid; r < R; r += 256) { s += ps[r * 128 + o]; q += pq[r * 128 + o]; }
#pragma unroll
    for (int off = 32; off; off >>= 1) { s += __shfl_down(s, off); q += __shfl_down(q, off); }
    __shared__ float rs[4], rq[4];
    if ((tid & 63) == 0) { rs[tid >> 6] = s; rq[tid >> 6] = q; }
    __syncthreads();
    if (tid == 0) {
        s = rs[0] + rs[1] + rs[2] + rs[3];
        q = rq[0] + rq[1] + rq[2] + rq[3];
        const float mean = s * (1.f / 65536.f);
        const float var = q * (1.f / 65536.f) - mean * mean;
        const float rstd = rsqrtf(var + 1e-6f);
        const float sc = g[o] * rstd;
        scl[o] = sc;
        sft[o] = be[o] - mean * sc;
    }
}

// ------------------------------------------- norm + ELU: bf16 in -> bf16 out (8 ch/thread)
__global__ __launch_bounds__(256) void k_norm_elu(
    const ushort* __restrict__ in, ushort* __restrict__ out,
    const float* __restrict__ scl, const float* __restrict__ sft)
{
    const int j = blockIdx.x * 256 + threadIdx.x;   // 1048576 groups of 8
    const uint4 pv = ((const uint4*)in)[j];
    const ushort* u = (const ushort*)&pv;
    const int o0 = (j & 15) << 3;
    ushort ro[8];
#pragma unroll
    for (int t = 0; t < 8; ++t) {
        const float x = b2f(u[t]);
        ro[t] = f2b(eluf(x * scl[o0 + t] + sft[o0 + t]));
    }
    ((uint4*)out)[j] = *(const uint4*)ro;
}

// ------------------------------------------- final: out = elu(x1 + norm(h2)), fp32 out
__global__ __launch_bounds__(256) void k_final(
    const ushort* __restrict__ x1b, const ushort* __restrict__ h2b,
    const float* __restrict__ scl, const float* __restrict__ sft,
    float* __restrict__ outp)
{
    const int j = blockIdx.x * 256 + threadIdx.x;   // 1048576 groups of 8
    const uint4 xv = ((const uint4*)x1b)[j];
    const uint4 hv = ((const uint4*)h2b)[j];
    const ushort* xu = (const ushort*)&xv;
    const ushort* hu = (const ushort*)&hv;
    const int o0 = (j & 15) << 3;
    float ro[8];
#pragma unroll
    for (int t = 0; t < 8; ++t) {
        const float a = b2f(xu[t]);
        const float h = b2f(hu[t]);
        ro[t] = eluf(a + h * scl[o0 + t] + sft[o0 + t]);
    }
    ((float4*)outp)[2 * j]     = *(const float4*)&ro[0];
    ((float4*)outp)[2 * j + 1] = *(const float4*)&ro[4];
}

extern "C" void kernel_launch(void* const* d_in, const int* in_sizes, int n_in,
                              void* d_out, int out_size, void* d_ws, size_t ws_size,
                              hipStream_t stream)
{
    const float* msa   = (const float*)d_in[0];
    const float* pairo = (const float*)d_in[1];
    const float* W1    = (const float*)d_in[2];
    const float* b1    = (const float*)d_in[3];
    const float* g_ln  = (const float*)d_in[4];
    const float* be_ln = (const float*)d_in[5];
    const float* W2    = (const float*)d_in[6];
    const float* b2    = (const float*)d_in[7];
    const float* Wc0   = (const float*)d_in[8];
    const float* g0    = (const float*)d_in[9];
    const float* be0   = (const float*)d_in[10];
    const float* Wr1   = (const float*)d_in[11];
    const float* g1    = (const float*)d_in[12];
    const float* be1   = (const float*)d_in[13];
    const float* Wr2   = (const float*)d_in[14];
    const float* g2    = (const float*)d_in[15];
    const float* be2   = (const float*)d_in[16];

    float* ws = (float*)d_ws;
    ushort* xdT   = (ushort*)ws;                    // 262144 f
    float* Ai     = ws + 294912;                    // 32768
    float* Bl     = ws + 327680;                    // 32768
    float* S1     = ws + 360448;                    // 128
    float* S2     = ws + 360576;                    // 128
    float* scl    = ws + 360704;                    // 128
    float* sft    = ws + 360832;                    // 128
    ushort* WCB   = (ushort*)(ws + 360960);         // 16384 f
    ushort* zbuf  = (ushort*)(ws + 377344);         // 128 f (256 bf16 zeros)
    ushort* G2swz = (ushort*)(ws + 393728);         // 65536 f
    float* ps     = ws + 590336;                    // 524288
    float* pq     = ws + 1114624;                   // 524288
    ushort* WB1   = (ushort*)(ws + 1638912);        // 73728 f
    ushort* WB2   = (ushort*)(ws + 1712640);        // 73728 f
    float* R1     = ws + 1786368;                   // 8388608 f
    float* R2     = ws + 10174976;                  // 8388608 f
    // R1: [first half] pair2B -> X2b ; [second half] X1b
    ushort* pair2B = (ushort*)R1;
    ushort* X2b    = (ushort*)R1;
    ushort* X1b    = (ushort*)(R1 + 4194304);
    // R2: [first half] X0b -> H2b ; [second half] Hb
    ushort* X0b = (ushort*)R2;
    ushort* H2b = (ushort*)R2;
    ushort* Hb  = (ushort*)(R2 + 4194304);

    k_prep<<<dim3(4224), dim3(256), 0, stream>>>(
        msa, W1, b1, xdT, W2, g_ln, be_ln, b2, S1, S2, G2swz,
        Wc0, WCB, zbuf, Ai, Bl, Wr1, WB1, Wr2, WB2);

    k_pairf<<<dim3(32, 64), dim3(256), 0, stream>>>(xdT, G2swz, S1, S2, pair2B);

    k_conv1x1m<<<dim3(1024), dim3(256), 0, stream>>>(pairo, pair2B, Ai, Bl, WCB, X0b, ps, pq);
    k_stats<<<dim3(128), dim3(256), 0, stream>>>(ps, pq, 1024, g0, be0, scl, sft);
    k_norm_elu<<<dim3(4096), dim3(256), 0, stream>>>(X0b, X1b, scl, sft);

    k_conv3x3m<<<dim3(2, 256), dim3(256), 0, stream>>>(X1b, WB1, zbuf, Hb, ps, pq);
    k_stats<<<dim3(128), dim3(256), 0, stream>>>(ps, pq, 512, g1, be1, scl, sft);
    k_norm_elu<<<dim3(4096), dim3(256), 0, stream>>>(Hb, X2b, scl, sft);

    k_conv3x3m<<<dim3(2, 256), dim3(256), 0, stream>>>(X2b, WB2, zbuf, H2b, ps, pq);
    k_stats<<<dim3(128), dim3(256), 0, stream>>>(ps, pq, 512, g2, be2, scl, sft);

    k_final<<<dim3(4096), dim3(256), 0, stream>>>(X1b, H2b, scl, sft, (float*)d_out);
}

// Round 8
// 308.051 us; speedup vs baseline: 1.6181x; 1.0063x over previous
//
#include <hip/hip_runtime.h>
#include <hip/hip_bf16.h>
#include <math.h>

// Shapes: B=1, N=64, L=256, nf=64, npj=32, nfo=128
// All GEMM-shaped work on bf16 MFMA (16x16x32). All intermediate activations bf16.
// Fragment conventions (validated rounds 1-7):
//   A-frag: row = lane&15, k = (lane>>4)*8 + j
//   B-frag: col = lane&15, k = (lane>>4)*8 + j
//   C-frag: col = lane&15, row = (lane>>4)*4 + r

typedef __attribute__((ext_vector_type(8))) short bf16x8;
typedef __attribute__((ext_vector_type(4))) float f32x4;

__device__ __forceinline__ float eluf(float x) { return x > 0.f ? x : expm1f(x); }
// native conversion -> compiler emits v_cvt_pk_bf16_f32 for pairs (guide m240)
__device__ __forceinline__ ushort f2b(float f) {
    __hip_bfloat16 h = __float2bfloat16(f);
    return *reinterpret_cast<ushort*>(&h);
}
__device__ __forceinline__ float b2f(ushort u) {
    return __uint_as_float(((unsigned)u) << 16);
}

// ================================================================ mega-prologue
// blocks: [0,2048) xdown | [2048,2176) g2 | [2176,2688) g2swz | [2688,2816) wcswz
//         [2816,3072) ab | [3072,3648) wswz1 | [3648,4224) wswz2
__global__ __launch_bounds__(256) void k_prep(
    const float* __restrict__ msa, const float* __restrict__ W1,
    const float* __restrict__ b1, ushort* __restrict__ xdT,
    const float* __restrict__ W2, const float* __restrict__ g_ln,
    const float* __restrict__ be_ln, const float* __restrict__ b2,
    float* __restrict__ S1, float* __restrict__ S2, ushort* __restrict__ G2swz,
    const float* __restrict__ Wc0, ushort* __restrict__ WCB, ushort* __restrict__ zbuf,
    float* __restrict__ Ai, float* __restrict__ Bl,
    const float* __restrict__ Wr1, ushort* __restrict__ WB1,
    const float* __restrict__ Wr2, ushort* __restrict__ WB2)
{
    __shared__ float smem[32 * 65];
    const int b = blockIdx.x, tid = threadIdx.x;
    if (b < 2048) {
        for (int t = tid; t < 2048; t += 256) smem[(t >> 6) * 65 + (t & 63)] = W1[t];
        __syncthreads();
        const int id = b * 256 + tid;
        const int p = id & 31, l = (id >> 5) & 255, n = id >> 13;
        const float* mrow = msa + (((n << 8) + l) << 6);
        const float* wrow = smem + p * 65;
        float s = 0.f;
#pragma unroll 8
        for (int f = 0; f < 64; ++f) s += mrow[f] * wrow[f];
        xdT[(((l << 5) + p) << 6) + n] = f2b(s + b1[p]);
    } else if (b < 2176) {
        const int o = b - 2048;
        float s1 = 0.f, s2 = 0.f;
        for (int c = tid; c < 1024; c += 256) {
            float w = W2[o * 1024 + c];
            s1 += g_ln[c] * w;
            s2 += be_ln[c] * w;
        }
#pragma unroll
        for (int off = 32; off; off >>= 1) { s1 += __shfl_down(s1, off); s2 += __shfl_down(s2, off); }
        __shared__ float r1[4], r2[4];
        if ((tid & 63) == 0) { r1[tid >> 6] = s1; r2[tid >> 6] = s2; }
        __syncthreads();
        if (tid == 0) {
            S1[o] = r1[0] + r1[1] + r1[2] + r1[3];
            S2[o] = r2[0] + r2[1] + r2[2] + r2[3] + b2[o];
        }
    } else if (b < 2688) {
        const int idx = (b - 2176) * 256 + tid;   // 131072
        const int j = idx & 7, lane = (idx >> 3) & 63, nt = (idx >> 9) & 7, kt = idx >> 12;
        const int k = kt * 32 + (lane >> 4) * 8 + j;
        const int o = nt * 16 + (lane & 15);
        G2swz[idx] = f2b(g_ln[k] * W2[o * 1024 + k]);
    } else if (b < 2816) {
        const int idx = (b - 2688) * 256 + tid;   // 32768
        const int j = idx & 7, lane = (idx >> 3) & 63, nt = (idx >> 9) & 7, ks = idx >> 12;
        const int ic = ks * 32 + (lane >> 4) * 8 + j;
        const int o = nt * 16 + (lane & 15);
        WCB[idx] = f2b(Wc0[o * 512 + ic]);
        if (idx < 128) zbuf[idx] = 0;
    } else if (b < 3072) {
        const int r = b - 2816;
        if (tid < 128) {
            const int c = tid;
            float v;
            if (c < 64) {
                float s = 0.f;
                for (int n = 0; n < 64; ++n) s += msa[(((n << 8) + r) << 6) + c];
                v = s * (1.f / 64.f);
            } else {
                v = msa[(r << 6) + (c - 64)];
            }
            smem[c] = v;
        }
        __syncthreads();
        const int o = tid & 127, half = tid >> 7;
        const float* wv = Wc0 + o * 512 + 256 + (half << 7);
        float a = 0.f;
#pragma unroll 4
        for (int c = 0; c < 128; ++c) a += smem[c] * wv[c];
        (half ? Bl : Ai)[r * 128 + o] = a;
    } else if (b < 3648) {
        const int idx = (b - 3072) * 256 + tid;   // 147456
        const int j = idx & 7, lane = (idx >> 3) & 63, nt = (idx >> 9) & 7;
        const int ks = (idx >> 12) & 3, tap = idx >> 14;
        const int ic = ks * 32 + (lane >> 4) * 8 + j;
        const int o = nt * 16 + (lane & 15);
        WB1[idx] = f2b(Wr1[o * 1152 + ic * 9 + tap]);
    } else {
        const int idx = (b - 3648) * 256 + tid;   // 147456
        const int j = idx & 7, lane = (idx >> 3) & 63, nt = (idx >> 9) & 7;
        const int ks = (idx >> 12) & 3, tap = idx >> 14;
        const int ic = ks * 32 + (lane >> 4) * 8 + j;
        const int o = nt * 16 + (lane & 15);
        WB2[idx] = f2b(Wr2[o * 1152 + ic * 9 + tap]);
    }
}

// ================================================================ fused pair path v2
// grid (32,64): bx = l-block (8 l), by = i-block (4 i) -> 32 px/block.
// Phase 1: outer GEMM, M=(l,q)=256 rows, N=(i,p)=128 cols, K=64 (operands swapped so
//          a lane's r=0..3 are consecutive q -> b64 packed LDS store).
// LDS layout: phys = px*2048 + (L ^ ((px&7)<<4) ^ (((L>>8)&3)<<4)), L = (p*32+q)*2.
// Phase 2: proj GEMM M=32px, N=128o, K=1024 from LDS; LN folded in epilogue.
__global__ __launch_bounds__(256, 2) void k_pairf(
    const ushort* __restrict__ xdT, const ushort* __restrict__ G2swz,
    const float* __restrict__ S1, const float* __restrict__ S2,
    ushort* __restrict__ pair2b)
{
    __shared__ ushort P_lds[32 * 1024];   // 64 KB
    __shared__ float mus[32], rstds[32];
    const int tid = threadIdx.x;
    const int w = tid >> 6, lane = tid & 63;
    const int lo = lane & 15, kg = lane >> 4;
    const int lb = blockIdx.x << 3;      // 8 l
    const int ib = blockIdx.y << 2;      // 4 i
    const int m_w = (w >> 1) << 7;       // M half (128 rows of (l,q))
    const int n_w = (w & 1) << 6;        // N half (64 cols of (i,p))

    f32x4 acc[8][4] = {};
#pragma unroll
    for (int ks = 0; ks < 2; ++ks) {
        bf16x8 a[8], b[4];
#pragma unroll
        for (int mt = 0; mt < 8; ++mt)
            a[mt] = *(const bf16x8*)&xdT[((lb << 5) + m_w + mt * 16 + lo) * 64 + ks * 32 + kg * 8];
#pragma unroll
        for (int nt = 0; nt < 4; ++nt)
            b[nt] = *(const bf16x8*)&xdT[((ib << 5) + n_w + nt * 16 + lo) * 64 + ks * 32 + kg * 8];
#pragma unroll
        for (int mt = 0; mt < 8; ++mt)
#pragma unroll
            for (int nt = 0; nt < 4; ++nt)
                acc[mt][nt] = __builtin_amdgcn_mfma_f32_16x16x32_bf16(a[mt], b[nt], acc[mt][nt], 0, 0, 0);
    }

    const float sc = 1.f / 64.f;
    // LN stats: wave covers 8 px = 4 l_loc (mt>>1) x 2 i_loc (nt>>1)
#pragma unroll
    for (int jj = 0; jj < 2; ++jj) {
#pragma unroll
        for (int ii = 0; ii < 4; ++ii) {
            float s = 0.f, q = 0.f;
#pragma unroll
            for (int dm = 0; dm < 2; ++dm)
#pragma unroll
                for (int dn = 0; dn < 2; ++dn)
#pragma unroll
                    for (int r = 0; r < 4; ++r) {
                        const float v = acc[ii * 2 + dm][jj * 2 + dn][r] * sc;
                        s += v; q += v * v;
                    }
#pragma unroll
            for (int off = 1; off < 64; off <<= 1) { s += __shfl_xor(s, off); q += __shfl_xor(q, off); }
            if (lane == 0) {
                const int l_loc = ((w >> 1) << 2) + ii;
                const int i_loc = ((w & 1) << 1) + jj;
                const int px = (i_loc << 3) + l_loc;
                const float mu = s * (1.f / 1024.f);
                const float var = q * (1.f / 1024.f) - mu * mu;
                mus[px] = mu;
                rstds[px] = rsqrtf(var + 1e-5f);
            }
        }
    }
    // P -> LDS: b64 packed (4 consecutive channels per lane)
#pragma unroll
    for (int mt = 0; mt < 8; ++mt) {
        const int mrow = m_w + mt * 16;
        const int l_loc = mrow >> 5;
        const int qb = (mrow & 31) + (kg << 2);
#pragma unroll
        for (int nt = 0; nt < 4; ++nt) {
            const int ncol = n_w + nt * 16;
            const int i_loc = ncol >> 5;
            const int p = (ncol & 31) + lo;
            const int px = (i_loc << 3) + l_loc;
            const int L = (p << 6) + (qb << 1);
            const int phys = (px << 11) + (L ^ ((px & 7) << 4) ^ (((L >> 8) & 3) << 4));
            ushort4 pk;
            pk.x = f2b(acc[mt][nt][0] * sc);
            pk.y = f2b(acc[mt][nt][1] * sc);
            pk.z = f2b(acc[mt][nt][2] * sc);
            pk.w = f2b(acc[mt][nt][3] * sc);
            *(ushort4*)((char*)P_lds + phys) = pk;
        }
    }
    __syncthreads();

    // Phase 2: wave w -> o-tiles {2w, 2w+1}, m-tiles {0,1} (px 0-15, 16-31)
    f32x4 pacc[2][2] = {};
#pragma unroll 4
    for (int ks = 0; ks < 32; ++ks) {
        const int L0 = (ks << 6) + (kg << 4);
        const int off0 = (L0 ^ ((lo & 7) << 4) ^ (((L0 >> 8) & 3) << 4));
        const bf16x8 a0 = *(const bf16x8*)((const char*)P_lds + (lo << 11) + off0);
        const bf16x8 a1 = *(const bf16x8*)((const char*)P_lds + ((16 + lo) << 11) + off0);
        const bf16x8 b0 = *(const bf16x8*)&G2swz[(((ks << 3) + (w << 1) + 0) * 64 + lane) * 8];
        const bf16x8 b1 = *(const bf16x8*)&G2swz[(((ks << 3) + (w << 1) + 1) * 64 + lane) * 8];
        pacc[0][0] = __builtin_amdgcn_mfma_f32_16x16x32_bf16(a0, b0, pacc[0][0], 0, 0, 0);
        pacc[0][1] = __builtin_amdgcn_mfma_f32_16x16x32_bf16(a0, b1, pacc[0][1], 0, 0, 0);
        pacc[1][0] = __builtin_amdgcn_mfma_f32_16x16x32_bf16(a1, b0, pacc[1][0], 0, 0, 0);
        pacc[1][1] = __builtin_amdgcn_mfma_f32_16x16x32_bf16(a1, b1, pacc[1][1], 0, 0, 0);
    }
#pragma unroll
    for (int mt2 = 0; mt2 < 2; ++mt2) {
#pragma unroll
        for (int j = 0; j < 2; ++j) {
            const int o = (((w << 1) + j) << 4) + lo;
            const float s1v = S1[o], s2v = S2[o];
#pragma unroll
            for (int r = 0; r < 4; ++r) {
                const int px = (mt2 << 4) + (kg << 2) + r;
                const int i = ib + (px >> 3), l = lb + (px & 7);
                pair2b[(((i << 8) + l) << 7) + o] = f2b(rstds[px] * (pacc[mt2][j][r] - mus[px] * s1v) + s2v);
            }
        }
    }
}

// ------------- 1x1 conv (MFMA): cat(pairo fp32, pair2B bf16) @ WCB + Ai + Bl, + IN partials
__global__ __launch_bounds__(256) void k_conv1x1m(
    const float* __restrict__ pairo, const ushort* __restrict__ pair2B,
    const float* __restrict__ Ai, const float* __restrict__ Bl,
    const ushort* __restrict__ WCB, ushort* __restrict__ X0b,
    float* __restrict__ ps, float* __restrict__ pq)
{
    const int tid = threadIdx.x;
    const int w = tid >> 6, lane = tid & 63;
    const int lo = lane & 15, kg = lane >> 4;
    const int m_w = (w >> 1) << 5;
    const int n_w = (w & 1) << 6;
    const int n4 = (w & 1) << 2;
    const int px0 = blockIdx.x << 6;
    const int iu = px0 >> 8;

    f32x4 acc[2][4] = {};
#pragma unroll
    for (int ks = 0; ks < 8; ++ks) {
        const int coff = (ks & 3) * 32 + kg * 8;
        bf16x8 a[2], b[4];
#pragma unroll
        for (int mt = 0; mt < 2; ++mt) {
            const int px = px0 + m_w + mt * 16 + lo;
            if (ks < 4) {
                const float4 f0 = *(const float4*)&pairo[px * 128 + coff];
                const float4 f1 = *(const float4*)&pairo[px * 128 + coff + 4];
                bf16x8 t;
                t[0] = (short)f2b(f0.x); t[1] = (short)f2b(f0.y);
                t[2] = (short)f2b(f0.z); t[3] = (short)f2b(f0.w);
                t[4] = (short)f2b(f1.x); t[5] = (short)f2b(f1.y);
                t[6] = (short)f2b(f1.z); t[7] = (short)f2b(f1.w);
                a[mt] = t;
            } else {
                a[mt] = *(const bf16x8*)&pair2B[px * 128 + coff];
            }
        }
#pragma unroll
        for (int nt = 0; nt < 4; ++nt)
            b[nt] = *(const bf16x8*)&WCB[((ks * 8 + n4 + nt) * 64 + lane) * 8];
#pragma unroll
        for (int mt = 0; mt < 2; ++mt)
#pragma unroll
            for (int nt = 0; nt < 4; ++nt)
                acc[mt][nt] = __builtin_amdgcn_mfma_f32_16x16x32_bf16(a[mt], b[nt], acc[mt][nt], 0, 0, 0);
    }

    float lsum[4] = {0.f, 0.f, 0.f, 0.f}, lsq[4] = {0.f, 0.f, 0.f, 0.f};
#pragma unroll
    for (int nt = 0; nt < 4; ++nt) {
        const int o = n_w + nt * 16 + lo;
        const float aadd = Ai[iu * 128 + o];
#pragma unroll
        for (int mt = 0; mt < 2; ++mt) {
#pragma unroll
            for (int r = 0; r < 4; ++r) {
                const int lpos = (px0 & 255) + m_w + mt * 16 + kg * 4 + r;
                const float v = acc[mt][nt][r] + aadd + Bl[lpos * 128 + o];
                X0b[((px0 + m_w + mt * 16 + kg * 4 + r) << 7) + o] = f2b(v);
                lsum[nt] += v; lsq[nt] += v * v;
            }
        }
    }
#pragma unroll
    for (int nt = 0; nt < 4; ++nt) {
        lsum[nt] += __shfl_xor(lsum[nt], 16); lsum[nt] += __shfl_xor(lsum[nt], 32);
        lsq[nt]  += __shfl_xor(lsq[nt], 16);  lsq[nt]  += __shfl_xor(lsq[nt], 32);
    }
    __shared__ float red_s[4][4][16], red_q[4][4][16];
    if (kg == 0) {
#pragma unroll
        for (int nt = 0; nt < 4; ++nt) { red_s[w][nt][lo] = lsum[nt]; red_q[w][nt][lo] = lsq[nt]; }
    }
    __syncthreads();
    if (tid < 128) {
        const int o = tid;
        const int half = o >> 6, nt = (o & 63) >> 4, lo2 = o & 15;
        const float s = red_s[half][nt][lo2] + red_s[half + 2][nt][lo2];
        const float q = red_q[half][nt][lo2] + red_q[half + 2][nt][lo2];
        ps[blockIdx.x * 128 + o] = s;
        pq[blockIdx.x * 128 + o] = q;
    }
}

// ------------- 3x3 conv (MFMA implicit im2col), 3-stage software pipeline, XCD-swizzled.
// grid 512 (flat): swz=(bid&7)*64 + bid>>3 -> y=swz>>1, xhalf=swz&1. Each XCD gets a
// contiguous 32-row band -> input rows stay L2-local per XCD.
__global__ __launch_bounds__(256, 2) void k_conv3x3m(
    const ushort* __restrict__ Xb, const ushort* __restrict__ WB,
    const ushort* __restrict__ zbuf,
    ushort* __restrict__ outb, float* __restrict__ ps, float* __restrict__ pq)
{
    const int tid = threadIdx.x;
    const int w = tid >> 6, lane = tid & 63;
    const int lo = lane & 15, kg = lane >> 4;
    const int m_w = (w >> 1) << 6;
    const int n_w = (w & 1) << 6;
    const int n4 = (w & 1) << 2;
    const int bid = blockIdx.x;
    const int swz = ((bid & 7) << 6) + (bid >> 3);
    const int y = swz >> 1;
    const int x0 = (swz & 1) << 7;
    const int zoff = (int)(zbuf - Xb) + kg * 8;

    int offs[9][4];
#pragma unroll
    for (int tap = 0; tap < 9; ++tap) {
        const int ky = tap / 3, kx = tap % 3;
        const int yy = y + ky - 1;
        const bool vy = (unsigned)yy < 256u;
        const int yc = vy ? yy : 0;
#pragma unroll
        for (int mt = 0; mt < 4; ++mt) {
            const int xx = x0 + m_w + mt * 16 + lo + kx - 1;
            const bool ok = vy && ((unsigned)xx < 256u);
            const int xc = xx < 0 ? 0 : (xx > 255 ? 255 : xx);
            offs[tap][mt] = ok ? ((((yc << 8) + xc) << 7) + kg * 8) : zoff;
        }
    }

    f32x4 acc[4][4] = {};
    bf16x8 A[3][4], B[3][4];

#define LOADS(S, SL)                                                              \
    {                                                                             \
        const int tap_ = (S) >> 2, ks_ = (S) & 3;                                 \
        _Pragma("unroll")                                                         \
        for (int mt = 0; mt < 4; ++mt)                                            \
            A[SL][mt] = *(const bf16x8*)&Xb[offs[tap_][mt] + ks_ * 32];           \
        _Pragma("unroll")                                                         \
        for (int nt = 0; nt < 4; ++nt)                                            \
            B[SL][nt] = *(const bf16x8*)&WB[(S) * 4096 + (n4 + nt) * 512 + lane * 8]; \
    }
#define MMAS(SL)                                                                  \
    {                                                                             \
        _Pragma("unroll")                                                         \
        for (int mt = 0; mt < 4; ++mt)                                            \
            _Pragma("unroll")                                                     \
            for (int nt = 0; nt < 4; ++nt)                                        \
                acc[mt][nt] = __builtin_amdgcn_mfma_f32_16x16x32_bf16(A[SL][mt], B[SL][nt], acc[mt][nt], 0, 0, 0); \
    }

    LOADS(0, 0);
    LOADS(1, 1);
#pragma unroll
    for (int s = 0; s < 36; ++s) {
        if (s + 2 < 36) {
            LOADS(s + 2, (s + 2) % 3);
        }
        MMAS(s % 3);
    }
#undef LOADS
#undef MMAS

    float lsum[4] = {0.f, 0.f, 0.f, 0.f}, lsq[4] = {0.f, 0.f, 0.f, 0.f};
#pragma unroll
    for (int nt = 0; nt < 4; ++nt) {
        const int o = n_w + nt * 16 + lo;
#pragma unroll
        for (int mt = 0; mt < 4; ++mt) {
#pragma unroll
            for (int r = 0; r < 4; ++r) {
                const int xo = x0 + m_w + mt * 16 + kg * 4 + r;
                const float v = acc[mt][nt][r];
                outb[(((y << 8) + xo) << 7) + o] = f2b(v);
                lsum[nt] += v; lsq[nt] += v * v;
            }
        }
    }
#pragma unroll
    for (int nt = 0; nt < 4; ++nt) {
        lsum[nt] += __shfl_xor(lsum[nt], 16); lsum[nt] += __shfl_xor(lsum[nt], 32);
        lsq[nt]  += __shfl_xor(lsq[nt], 16);  lsq[nt]  += __shfl_xor(lsq[nt], 32);
    }
    __shared__ float red_s[4][4][16], red_q[4][4][16];
    if (kg == 0) {
#pragma unroll
        for (int nt = 0; nt < 4; ++nt) { red_s[w][nt][lo] = lsum[nt]; red_q[w][nt][lo] = lsq[nt]; }
    }
    __syncthreads();
    if (tid < 128) {
        const int o = tid;
        const int half = o >> 6, nt = (o & 63) >> 4, lo2 = o & 15;
        const float s = red_s[half][nt][lo2] + red_s[half + 2][nt][lo2];
        const float q = red_q[half][nt][lo2] + red_q[half + 2][nt][lo2];
        ps[swz * 128 + o] = s;
        pq[swz * 128 + o] = q;
    }
}

// ------------------------------------------- per-channel IN params
__global__ __launch_bounds__(256) void k_stats(
    const float* __restrict__ ps, const float* __restrict__ pq, int R,
    const float* __restrict__ g, const float* __restrict__ be,
    float* __restrict__ scl, float* __restrict__ sft)
{
    const int o = blockIdx.x, tid = threadIdx.x;
    float s = 0.f, q = 0.f;
    for (int r = tid; r < R; r += 256) { s += ps[r * 128 + o]; q += pq[r * 128 + o]; }
#pragma unroll
    for (int off = 32; off; off >>= 1) { s += __shfl_down(s, off); q += __shfl_down(q, off); }
    __shared__ float rs[4], rq[4];
    if ((tid & 63) == 0) { rs[tid >> 6] = s; rq[tid >> 6] = q; }
    __syncthreads();
    if (tid == 0) {
        s = rs[0] + rs[1] + rs[2] + rs[3];
        q = rq[0] + rq[1] + rq[2] + rq[3];
        const float mean = s * (1.f / 65536.f);
        const float var = q * (1.f / 65536.f) - mean * mean;
        const float rstd = rsqrtf(var + 1e-6f);
        const float sc = g[o] * rstd;
        scl[o] = sc;
        sft[o] = be[o] - mean * sc;
    }
}

// ------------------------------------------- norm + ELU: bf16 in -> bf16 out (8 ch/thread)
__global__ __launch_bounds__(256) void k_norm_elu(
    const ushort* __restrict__ in, ushort* __restrict__ out,
    const float* __restrict__ scl, const float* __restrict__ sft)
{
    const int j = blockIdx.x * 256 + threadIdx.x;   // 1048576 groups of 8
    const uint4 pv = ((const uint4*)in)[j];
    const ushort* u = (const ushort*)&pv;
    const int o0 = (j & 15) << 3;
    ushort ro[8];
#pragma unroll
    for (int t = 0; t < 8; ++t) {
        const float x = b2f(u[t]);
        ro[t] = f2b(eluf(x * scl[o0 + t] + sft[o0 + t]));
    }
    ((uint4*)out)[j] = *(const uint4*)ro;
}

// ------------------------------------------- final: out = elu(x1 + norm(h2)), fp32 out
__global__ __launch_bounds__(256) void k_final(
    const ushort* __restrict__ x1b, const ushort* __restrict__ h2b,
    const float* __restrict__ scl, const float* __restrict__ sft,
    float* __restrict__ outp)
{
    const int j = blockIdx.x * 256 + threadIdx.x;   // 1048576 groups of 8
    const uint4 xv = ((const uint4*)x1b)[j];
    const uint4 hv = ((const uint4*)h2b)[j];
    const ushort* xu = (const ushort*)&xv;
    const ushort* hu = (const ushort*)&hv;
    const int o0 = (j & 15) << 3;
    float ro[8];
#pragma unroll
    for (int t = 0; t < 8; ++t) {
        const float a = b2f(xu[t]);
        const float h = b2f(hu[t]);
        ro[t] = eluf(a + h * scl[o0 + t] + sft[o0 + t]);
    }
    ((float4*)outp)[2 * j]     = *(const float4*)&ro[0];
    ((float4*)outp)[2 * j + 1] = *(const float4*)&ro[4];
}

extern "C" void kernel_launch(void* const* d_in, const int* in_sizes, int n_in,
                              void* d_out, int out_size, void* d_ws, size_t ws_size,
                              hipStream_t stream)
{
    const float* msa   = (const float*)d_in[0];
    const float* pairo = (const float*)d_in[1];
    const float* W1    = (const float*)d_in[2];
    const float* b1    = (const float*)d_in[3];
    const float* g_ln  = (const float*)d_in[4];
    const float* be_ln = (const float*)d_in[5];
    const float* W2    = (const float*)d_in[6];
    const float* b2    = (const float*)d_in[7];
    const float* Wc0   = (const float*)d_in[8];
    const float* g0    = (const float*)d_in[9];
    const float* be0   = (const float*)d_in[10];
    const float* Wr1   = (const float*)d_in[11];
    const float* g1    = (const float*)d_in[12];
    const float* be1   = (const float*)d_in[13];
    const float* Wr2   = (const float*)d_in[14];
    const float* g2    = (const float*)d_in[15];
    const float* be2   = (const float*)d_in[16];

    float* ws = (float*)d_ws;
    ushort* xdT   = (ushort*)ws;                    // 262144 f
    float* Ai     = ws + 294912;                    // 32768
    float* Bl     = ws + 327680;                    // 32768
    float* S1     = ws + 360448;                    // 128
    float* S2     = ws + 360576;                    // 128
    float* scl    = ws + 360704;                    // 128
    float* sft    = ws + 360832;                    // 128
    ushort* WCB   = (ushort*)(ws + 360960);         // 16384 f
    ushort* zbuf  = (ushort*)(ws + 377344);         // 128 f (256 bf16 zeros)
    ushort* G2swz = (ushort*)(ws + 393728);         // 65536 f
    float* ps     = ws + 590336;                    // 524288
    float* pq     = ws + 1114624;                   // 524288
    ushort* WB1   = (ushort*)(ws + 1638912);        // 73728 f
    ushort* WB2   = (ushort*)(ws + 1712640);        // 73728 f
    float* R1     = ws + 1786368;                   // 8388608 f
    float* R2     = ws + 10174976;                  // 8388608 f
    // R1: [first half] pair2B -> X2b ; [second half] X1b
    ushort* pair2B = (ushort*)R1;
    ushort* X2b    = (ushort*)R1;
    ushort* X1b    = (ushort*)(R1 + 4194304);
    // R2: [first half] X0b -> H2b ; [second half] Hb
    ushort* X0b = (ushort*)R2;
    ushort* H2b = (ushort*)R2;
    ushort* Hb  = (ushort*)(R2 + 4194304);

    k_prep<<<dim3(4224), dim3(256), 0, stream>>>(
        msa, W1, b1, xdT, W2, g_ln, be_ln, b2, S1, S2, G2swz,
        Wc0, WCB, zbuf, Ai, Bl, Wr1, WB1, Wr2, WB2);

    k_pairf<<<dim3(32, 64), dim3(256), 0, stream>>>(xdT, G2swz, S1, S2, pair2B);

    k_conv1x1m<<<dim3(1024), dim3(256), 0, stream>>>(pairo, pair2B, Ai, Bl, WCB, X0b, ps, pq);
    k_stats<<<dim3(128), dim3(256), 0, stream>>>(ps, pq, 1024, g0, be0, scl, sft);
    k_norm_elu<<<dim3(4096), dim3(256), 0, stream>>>(X0b, X1b, scl, sft);

    k_conv3x3m<<<dim3(512), dim3(256), 0, stream>>>(X1b, WB1, zbuf, Hb, ps, pq);
    k_stats<<<dim3(128), dim3(256), 0, stream>>>(ps, pq, 512, g1, be1, scl, sft);
    k_norm_elu<<<dim3(4096), dim3(256), 0, stream>>>(Hb, X2b, scl, sft);

    k_conv3x3m<<<dim3(512), dim3(256), 0, stream>>>(X2b, WB2, zbuf, H2b, ps, pq);
    k_stats<<<dim3(128), dim3(256), 0, stream>>>(ps, pq, 512, g2, be2, scl, sft);

    k_final<<<dim3(4096), dim3(256), 0, stream>>>(X1b, H2b, scl, sft, (float*)d_out);
}